// Round 9
// baseline (468.909 us; speedup 1.0000x reference)
//
#include <hip/hip_runtime.h>
#include <math.h>

#define Bb 64
#define N0 1024
#define NE 16384
#define Fd 128
#define K1 512
#define K2 256
#define RPB 256  // rows per k_graph block

__device__ __forceinline__ float wred_sum(float v) {
#pragma unroll
  for (int o = 32; o > 0; o >>= 1) v += __shfl_down(v, o, 64);
  return v;
}
__device__ __forceinline__ float wred_sum_all(float v) {
#pragma unroll
  for (int o = 32; o > 0; o >>= 1) v += __shfl_xor(v, o, 64);
  return v;
}
__device__ __forceinline__ float wred_max_all(float v) {
#pragma unroll
  for (int o = 32; o > 0; o >>= 1) v = fmaxf(v, __shfl_xor(v, o, 64));
  return v;
}

// ---- fused graph build: edges -> LDS bitmask -> adj + degree + nbr list ----
__global__ __launch_bounds__(1024) void k_graph(const int* __restrict__ src,
    const int* __restrict__ dst, unsigned* __restrict__ adj,
    unsigned short* __restrict__ nbr, int* __restrict__ degv,
    float* __restrict__ dis0, float* __restrict__ dis1) {
  __shared__ unsigned lmask[RPB * 32];  // 32 KB
  int t = threadIdx.x;
  int b = blockIdx.x >> 2;
  int rlo = (blockIdx.x & 3) * RPB;
#pragma unroll
  for (int i = t; i < RPB * 32; i += 1024) lmask[i] = 0;
  __syncthreads();
  const int* sp = src + b * NE;
  const int* dp = dst + b * NE;
#pragma unroll
  for (int e = t; e < NE; e += 1024) {
    int u = sp[e], v = dp[e];
    if (u == v) continue;
    if ((unsigned)(u - rlo) < RPB)
      atomicOr(&lmask[(u - rlo) * 32 + (v >> 5)], 1u << (v & 31));
    if ((unsigned)(v - rlo) < RPB)
      atomicOr(&lmask[(v - rlo) * 32 + (u >> 5)], 1u << (u & 31));
  }
  __syncthreads();
  unsigned* adjg = adj + ((size_t)(b << 10) + rlo) * 32;
#pragma unroll
  for (int i = t; i < RPB * 32; i += 1024) adjg[i] = lmask[i];
  if (t < RPB) {
    int row = (b << 10) + rlo + t;
    const unsigned* wm = &lmask[t * 32];
    int d = 0;
#pragma unroll
    for (int i = 0; i < 32; ++i) d += __popc(wm[i]);
    degv[row] = d;
    dis0[row] = d > 0 ? rsqrtf((float)d) : 0.f;
    dis1[row] = rsqrtf((float)(d + 1));
    unsigned short* dstp = nbr + (size_t)row * 128;
    int o = 0;
#pragma unroll
    for (int w = 0; w < 32; ++w) {
      unsigned m = wm[w];
      int bas = w << 5;
      while (m) { int j = bas + __ffs(m) - 1; m &= m - 1; dstp[o++] = (unsigned short)j; }
    }
  }
}

// ---- C[M,128] = X[M,128] @ W[128,128], M % 64 == 0, grid = M/64, block 256 ----
__global__ __launch_bounds__(256) void k_gemm128(const float* __restrict__ X,
                                                 const float* __restrict__ W,
                                                 float* __restrict__ C) {
  __shared__ float Xs[64][132];
  __shared__ float Ws[32][132];
  int t = threadIdx.x;
  size_t row0 = (size_t)blockIdx.x * 64;
  const float4* Xg = (const float4*)(X + row0 * Fd);
#pragma unroll
  for (int i = 0; i < 8; ++i) {
    int f4 = t + 256 * i;
    float4 v = Xg[f4];
    *(float4*)&Xs[f4 >> 5][(f4 & 31) * 4] = v;
  }
  int r0 = (t >> 5) * 8, c0 = (t & 31) * 4;
  float acc[8][4] = {};
  for (int kb = 0; kb < 128; kb += 32) {
    __syncthreads();
#pragma unroll
    for (int i = 0; i < 4; ++i) {
      int f4 = t + 256 * i;
      float4 v = ((const float4*)(W + (size_t)kb * Fd))[f4];
      *(float4*)&Ws[f4 >> 5][(f4 & 31) * 4] = v;
    }
    __syncthreads();
#pragma unroll
    for (int k = 0; k < 32; ++k) {
      float4 wv = *(const float4*)&Ws[k][c0];
#pragma unroll
      for (int i = 0; i < 8; ++i) {
        float xv = Xs[r0 + i][kb + k];
        acc[i][0] += xv * wv.x; acc[i][1] += xv * wv.y;
        acc[i][2] += xv * wv.z; acc[i][3] += xv * wv.w;
      }
    }
  }
#pragma unroll
  for (int i = 0; i < 8; ++i) {
    float4 o = make_float4(acc[i][0], acc[i][1], acc[i][2], acc[i][3]);
    *(float4*)&C[(row0 + r0 + i) * Fd + c0] = o;
  }
}

// ---- conv1 via LDS-staged source: one block = (graph, 16-col slice) ----
// Stage dis1-scaled XW[1024][16cols] in LDS; gathers become LDS adds.
__global__ __launch_bounds__(1024) void k_conv1b(const unsigned short* __restrict__ nbr,
    const int* __restrict__ degv, const float* __restrict__ XW,
    const float* __restrict__ dis1, const float* __restrict__ b1,
    float* __restrict__ h1) {
  __shared__ float Xs[N0 * 16];  // 64 KB
  int t = threadIdx.x;
  int g = blockIdx.x & 63;       // graph -> XCD residue g&7 (all 8 cb-blocks co-XCD)
  int cb = blockIdx.x >> 6;      // 0..7 col-block
  int c16 = cb * 16;
  const float* XWg = XW + ((size_t)(g << 10)) * Fd + c16;
  const float* d1g = dis1 + (g << 10);
  {
    int r = t >> 2, c4 = (t & 3) * 4;
#pragma unroll
    for (int p = 0; p < 4; ++p) {
      int row = r + p * 256;
      float4 v = *(const float4*)&XWg[(size_t)row * Fd + c4];
      float s = d1g[row];
      v.x *= s; v.y *= s; v.z *= s; v.w *= s;
      *(float4*)&Xs[row * 16 + c4] = v;
    }
  }
  __syncthreads();
  int col = t & 15, rsl = t >> 4;  // 64 row-slots x 16 cols
  const unsigned short* nb = nbr + (((size_t)(g << 10)) << 7);
  float bcol = b1[c16 + col];
  for (int rg = 0; rg < 16; ++rg) {
    int lrow = rg * 64 + rsl;
    int grow = (g << 10) + lrow;
    int deg = degv[grow];
    const unsigned short* nr = nb + ((size_t)lrow << 7);
    float acc = 0.f;
    int dp = deg & ~7;
    int i = 0;
    for (; i < dp; i += 8) {
      int jj[8];
#pragma unroll
      for (int u = 0; u < 8; ++u) jj[u] = nr[i + u];
      float vv[8];
#pragma unroll
      for (int u = 0; u < 8; ++u) vv[u] = Xs[jj[u] * 16 + col];
#pragma unroll
      for (int u = 0; u < 8; ++u) acc += vv[u];
    }
    for (; i < deg; ++i) acc += Xs[nr[i] * 16 + col];
    float di = d1g[lrow];
    float self = Xs[lrow * 16 + col];  // = dis1_row * XW_row_col
    h1[(size_t)grow * Fd + c16 + col] = fmaxf(di * (acc + self) + bcol, 0.f);
  }
}

// ---- NIS via LDS-staged source; partial |.|-sums per (row, col-block) ----
__global__ __launch_bounds__(1024) void k_nis1b(const unsigned short* __restrict__ nbr,
    const int* __restrict__ degv, const float* __restrict__ h,
    const float* __restrict__ dis0, float* __restrict__ partial) {
  __shared__ float Xs[N0 * 16];  // 64 KB
  int t = threadIdx.x;
  int g = blockIdx.x & 63;
  int cb = blockIdx.x >> 6;
  int c16 = cb * 16;
  const float* hg = h + ((size_t)(g << 10)) * Fd + c16;
  const float* d0g = dis0 + (g << 10);
  {
    int r = t >> 2, c4 = (t & 3) * 4;
#pragma unroll
    for (int p = 0; p < 4; ++p) {
      int row = r + p * 256;
      float4 v = *(const float4*)&hg[(size_t)row * Fd + c4];
      float s = d0g[row];
      v.x *= s; v.y *= s; v.z *= s; v.w *= s;
      *(float4*)&Xs[row * 16 + c4] = v;
    }
  }
  __syncthreads();
  int col = t & 15, rsl = t >> 4;
  const unsigned short* nb = nbr + (((size_t)(g << 10)) << 7);
  for (int rg = 0; rg < 16; ++rg) {
    int lrow = rg * 64 + rsl;
    int grow = (g << 10) + lrow;
    int deg = degv[grow];
    const unsigned short* nr = nb + ((size_t)lrow << 7);
    float acc = 0.f;
    int dp = deg & ~7;
    int i = 0;
    for (; i < dp; i += 8) {
      int jj[8];
#pragma unroll
      for (int u = 0; u < 8; ++u) jj[u] = nr[i + u];
      float vv[8];
#pragma unroll
      for (int u = 0; u < 8; ++u) vv[u] = Xs[jj[u] * 16 + col];
#pragma unroll
      for (int u = 0; u < 8; ++u) acc += vv[u];
    }
    for (; i < deg; ++i) acc += Xs[nr[i] * 16 + col];
    float hv = hg[(size_t)lrow * Fd + col];
    float p = fabsf(hv - d0g[lrow] * acc);
    // reduce over the 16-lane col group
    p += __shfl_xor(p, 1, 64);
    p += __shfl_xor(p, 2, 64);
    p += __shfl_xor(p, 4, 64);
    p += __shfl_xor(p, 8, 64);
    if (col == 0) partial[(size_t)grow * 8 + cb] = p;
  }
}

__global__ void k_nisred(const float* __restrict__ partial, float* __restrict__ score,
                         int total) {
  int row = blockIdx.x * 256 + threadIdx.x;
  if (row >= total) return;
  float4 a = *(const float4*)&partial[(size_t)row * 8];
  float4 b = *(const float4*)&partial[(size_t)row * 8 + 4];
  score[row] = a.x + a.y + a.z + a.w + b.x + b.y + b.z + b.w;
}

// ---- exact top-k per graph: bitonic sort of (score,idx) packed u64 keys ----
__global__ __launch_bounds__(1024) void k_topk(const float* __restrict__ score,
                                               int* __restrict__ perm, int n, int k) {
  __shared__ unsigned long long keys[1024];
  int b = blockIdx.x, t = threadIdx.x;
  float s = score[b * n + t];
  unsigned ub = __float_as_uint(s);
  unsigned su = (ub & 0x80000000u) ? ~ub : (ub | 0x80000000u);  // monotone map
  keys[t] = ((unsigned long long)(~su) << 32) | (unsigned)t;    // asc sort = desc score, asc idx
  __syncthreads();
  for (int kk = 2; kk <= n; kk <<= 1) {
    for (int j = kk >> 1; j > 0; j >>= 1) {
      int ixj = t ^ j;
      if (ixj > t) {
        unsigned long long a = keys[t], c = keys[ixj];
        bool up = ((t & kk) == 0);
        if ((a > c) == up) { keys[t] = c; keys[ixj] = a; }
      }
      __syncthreads();
    }
  }
  if (t < k) perm[b * k + t] = (int)(keys[t] & 0xffffffffu);
}

// ---- gather pooled rows + attention dots ----
__global__ __launch_bounds__(128) void k_gather(const float* __restrict__ h,
    const int* __restrict__ perm, const float* __restrict__ att, float* __restrict__ Xp,
    float* __restrict__ ar, float* __restrict__ ac, int n, int k) {
  int idx = blockIdx.x, f = threadIdx.x;
  int b = idx / k;
  __shared__ float red[4];
  int p = perm[idx];
  float v = h[((size_t)b * n + p) * Fd + f];
  Xp[(size_t)idx * Fd + f] = v;
  float r1 = wred_sum(v * att[f]);
  float r2 = wred_sum(v * att[Fd + f]);
  if ((f & 63) == 0) { red[f >> 6] = r1; red[2 + (f >> 6)] = r2; }
  __syncthreads();
  if (f == 0) { ar[idx] = red[0] + red[1]; ac[idx] = red[2] + red[3]; }
}

// ---- readout: g[b][0:128] (+)= relu(max), g[b][128:256] (+)= relu(mean) ----
__global__ __launch_bounds__(1024) void k_readout(const float* __restrict__ X, int n,
                                                  float* __restrict__ g, int init) {
  int b = blockIdx.x, t = threadIdx.x;
  int f = t & 127, rs = t >> 7;
  __shared__ float smax[8][128];
  __shared__ float ssum[8][128];
  int per = n >> 3;
  const float* Xs = X + ((size_t)b * n + (size_t)rs * per) * Fd + f;
  float mx = -3.0e38f, sm = 0.f;
  for (int j = 0; j < per; j += 8) {
    float vv[8];
#pragma unroll
    for (int u = 0; u < 8; ++u) vv[u] = Xs[(size_t)(j + u) * Fd];
#pragma unroll
    for (int u = 0; u < 8; ++u) { mx = fmaxf(mx, vv[u]); sm += vv[u]; }
  }
  smax[rs][f] = mx; ssum[rs][f] = sm;
  __syncthreads();
  if (t < 128) {
    float m = smax[0][f], s = ssum[0][f];
#pragma unroll
    for (int q = 1; q < 8; ++q) { m = fmaxf(m, smax[q][f]); s += ssum[q][f]; }
    float a = fmaxf(m, 0.f);
    float m2 = fmaxf(s / (float)n, 0.f);
    if (init) { g[b * 384 + f] = a; g[b * 384 + 128 + f] = m2; }
    else      { g[b * 384 + f] += a; g[b * 384 + 128 + f] += m2; }
  }
}

// ---- A1 = softmax_row(leakyrelu(ar_i+ac_j) + bit(pi,pj)) + row stats ----
__global__ __launch_bounds__(256) void k_buildA_bit(const unsigned* __restrict__ adj,
    const int* __restrict__ perm, const float* __restrict__ ar, const float* __restrict__ ac,
    float* __restrict__ A, float* __restrict__ disc, float* __restrict__ saO,
    float* __restrict__ disn, float* __restrict__ diagO) {
  int wid = threadIdx.x >> 6, lane = threadIdx.x & 63;
  int row = blockIdx.x * 4 + wid;      // [0, Bb*K1)
  int b = row >> 9, i = row & (K1 - 1);
  int pbase = b << 9;
  int pi = perm[pbase + i];
  float ari = ar[pbase + i];
  int j0 = lane * 8;
  float acv[8]; int pj[8];
  *(float4*)&acv[0] = *(const float4*)&ac[pbase + j0];
  *(float4*)&acv[4] = *(const float4*)&ac[pbase + j0 + 4];
  *(int4*)&pj[0] = *(const int4*)&perm[pbase + j0];
  *(int4*)&pj[4] = *(const int4*)&perm[pbase + j0 + 4];
  const unsigned* arow = adj + (size_t)((b << 10) + pi) * 32;
  float xv[8];
#pragma unroll
  for (int u = 0; u < 8; ++u) {
    float x = ari + acv[u];
    x = x > 0.f ? x : 0.2f * x;
    unsigned word = arow[pj[u] >> 5];
    xv[u] = x + (float)((word >> (pj[u] & 31)) & 1u);
  }
  float m = xv[0];
#pragma unroll
  for (int u = 1; u < 8; ++u) m = fmaxf(m, xv[u]);
  m = wred_max_all(m);
  float e[8], ls = 0.f;
#pragma unroll
  for (int u = 0; u < 8; ++u) { e[u] = expf(xv[u] - m); ls += e[u]; }
  float s = wred_sum_all(ls);
  float inv = 1.0f / s;
  float av[8]; float lsum = 0.f;
#pragma unroll
  for (int u = 0; u < 8; ++u) { av[u] = e[u] * inv; lsum += av[u]; }
  float* Ar = A + (size_t)row * K1 + j0;
  *(float4*)&Ar[0] = make_float4(av[0], av[1], av[2], av[3]);
  *(float4*)&Ar[4] = make_float4(av[4], av[5], av[6], av[7]);
  float rs = wred_sum_all(lsum);
  float dsel = av[i & 7];                 // uniform index
  float dval = __shfl(dsel, i >> 3, 64);
  if (lane == 0) {
    float sav = (dval == 0.f) ? 1.f : 0.f;
    float deg = rs + sav;
    disc[row] = deg > 0.f ? rsqrtf(deg) : 0.f;
    saO[row] = sav;
    float deg0 = rs - dval;
    disn[row] = deg0 > 0.f ? rsqrtf(deg0) : 0.f;
    diagO[row] = dval;
  }
}

// ---- A2 = softmax_row(leakyrelu(ar_i+ac_j) + A1[pi,pj]) + row stats ----
__global__ __launch_bounds__(256) void k_buildA_dense(const float* __restrict__ Aprev,
    const int* __restrict__ perm, const float* __restrict__ ar, const float* __restrict__ ac,
    float* __restrict__ A, float* __restrict__ disc, float* __restrict__ saO,
    float* __restrict__ disn, float* __restrict__ diagO) {
  int wid = threadIdx.x >> 6, lane = threadIdx.x & 63;
  int row = blockIdx.x * 4 + wid;      // [0, Bb*K2)
  int b = row >> 8, i = row & (K2 - 1);
  int pbase = b << 8;
  int pi = perm[pbase + i];
  float ari = ar[pbase + i];
  int j0 = lane * 4;
  float acv[4]; int pj[4];
  *(float4*)&acv[0] = *(const float4*)&ac[pbase + j0];
  *(int4*)&pj[0] = *(const int4*)&perm[pbase + j0];
  const float* aprow = Aprev + (size_t)((b << 9) + pi) * K1;
  float xv[4];
#pragma unroll
  for (int u = 0; u < 4; ++u) {
    float x = ari + acv[u];
    x = x > 0.f ? x : 0.2f * x;
    xv[u] = x + aprow[pj[u]];
  }
  float m = fmaxf(fmaxf(xv[0], xv[1]), fmaxf(xv[2], xv[3]));
  m = wred_max_all(m);
  float e[4], ls = 0.f;
#pragma unroll
  for (int u = 0; u < 4; ++u) { e[u] = expf(xv[u] - m); ls += e[u]; }
  float s = wred_sum_all(ls);
  float inv = 1.0f / s;
  float av[4]; float lsum = 0.f;
#pragma unroll
  for (int u = 0; u < 4; ++u) { av[u] = e[u] * inv; lsum += av[u]; }
  *(float4*)&A[(size_t)row * K2 + j0] = make_float4(av[0], av[1], av[2], av[3]);
  float rs = wred_sum_all(lsum);
  float dsel = av[i & 3];
  float dval = __shfl(dsel, i >> 2, 64);
  if (lane == 0) {
    float sav = (dval == 0.f) ? 1.f : 0.f;
    float deg = rs + sav;
    disc[row] = deg > 0.f ? rsqrtf(deg) : 0.f;
    saO[row] = sav;
    float deg0 = rs - dval;
    disn[row] = deg0 > 0.f ? rsqrtf(deg0) : 0.f;
    diagO[row] = dval;
  }
}

// ---- fused dense mm: out = epilogue(A[b] @ diag(wrow) Y[b]) ----
// BM=64, BN=64 (2 col-tiles), split-K x2 (512 threads).
template <int MODE>
__global__ __launch_bounds__(512) void k_mmf(const float* __restrict__ A,
    const float* __restrict__ Y, const float* __restrict__ wrow,
    const float* __restrict__ aux, const float* __restrict__ bias,
    float* __restrict__ outp, int n) {
  __shared__ float smem[8960];  // As[2][64][36] @0 (4608), Ys[2][32][68] @4608 (4352)
  int t = threadIdx.x;
  int kg = t >> 8, tt = t & 255;
  int tiles2 = (n >> 6) << 1;    // row-tiles * 2 col-tiles
  int bid = blockIdx.x;
  int c = bid & 7, q = bid >> 3;
  int g = c * 8 + q / tiles2;    // graph (8 graphs per XCD)
  int rem = q % tiles2;
  int rt = rem >> 1, ct = rem & 1;
  const float* Ab = A + (size_t)g * n * n + (size_t)(rt * 64) * n;
  const float* Yb = Y + (size_t)g * n * Fd + ct * 64;
  const float* wb = wrow + (size_t)g * n;
  int r0 = (tt >> 4) * 4, c0 = (tt & 15) * 4;
  float acc[4][4] = {};
  int kbase = kg * (n >> 1);
  float* Asg = smem + kg * 2304;
  float* Ysg = smem + 4608 + kg * 2176;
  for (int kb = 0; kb < (n >> 1); kb += 32) {
    int kglob = kbase + kb;
    __syncthreads();
#pragma unroll
    for (int ii = 0; ii < 2; ++ii) {
      int f4 = tt + 256 * ii;
      int r = f4 >> 3, c4 = (f4 & 7) * 4;
      *(float4*)&Asg[r * 36 + c4] = *(const float4*)&Ab[(size_t)r * n + kglob + c4];
    }
#pragma unroll
    for (int ii = 0; ii < 2; ++ii) {
      int f4 = tt + 256 * ii;
      int r = f4 >> 4, c4 = (f4 & 15) * 4;
      float4 v = *(const float4*)&Yb[(size_t)(kglob + r) * Fd + c4];
      float sc = wb[kglob + r];
      v.x *= sc; v.y *= sc; v.z *= sc; v.w *= sc;
      *(float4*)&Ysg[r * 68 + c4] = v;
    }
    __syncthreads();
#pragma unroll
    for (int k4 = 0; k4 < 8; ++k4) {
      float a_[4][4];
#pragma unroll
      for (int i = 0; i < 4; ++i)
        *(float4*)a_[i] = *(const float4*)&Asg[(r0 + i) * 36 + k4 * 4];
#pragma unroll
      for (int kk = 0; kk < 4; ++kk) {
        float4 y = *(const float4*)&Ysg[(k4 * 4 + kk) * 68 + c0];
#pragma unroll
        for (int i = 0; i < 4; ++i) {
          float av = a_[i][kk];
          acc[i][0] += av * y.x; acc[i][1] += av * y.y;
          acc[i][2] += av * y.z; acc[i][3] += av * y.w;
        }
      }
    }
  }
  float* mrg = smem;
  __syncthreads();
  if (kg == 1) {
#pragma unroll
    for (int i = 0; i < 4; ++i)
      *(float4*)&mrg[(r0 + i) * 64 + c0] = *(float4*)&acc[i][0];
  }
  __syncthreads();
  if (kg == 0) {
#pragma unroll
    for (int i = 0; i < 4; ++i) {
      float4 m0 = *(float4*)&mrg[(r0 + i) * 64 + c0];
      acc[i][0] += m0.x; acc[i][1] += m0.y; acc[i][2] += m0.z; acc[i][3] += m0.w;
    }
    if (MODE == 0) {
      float4 bv = *(const float4*)&bias[ct * 64 + c0];
#pragma unroll
      for (int i = 0; i < 4; ++i) {
        int rl = rt * 64 + r0 + i;
        size_t R = (size_t)g * n + rl;
        float dc = wb[rl];
        float sv = aux[R] * dc;
        float4 y = *(const float4*)&Y[R * Fd + ct * 64 + c0];
        float4 o;
        o.x = fmaxf(dc * (acc[i][0] + sv * y.x) + bv.x, 0.f);
        o.y = fmaxf(dc * (acc[i][1] + sv * y.y) + bv.y, 0.f);
        o.z = fmaxf(dc * (acc[i][2] + sv * y.z) + bv.z, 0.f);
        o.w = fmaxf(dc * (acc[i][3] + sv * y.w) + bv.w, 0.f);
        *(float4*)&outp[R * Fd + ct * 64 + c0] = o;
      }
    } else {
      float* rowred = smem + 4608;  // Ys region dead; [64][16]
#pragma unroll
      for (int i = 0; i < 4; ++i) {
        int rl = rt * 64 + r0 + i;
        size_t R = (size_t)g * n + rl;
        float dn = wb[rl];
        float dg = aux[R] * dn;
        float4 h = *(const float4*)&Y[R * Fd + ct * 64 + c0];
        float p = 0.f;
        p += fabsf(h.x - dn * (acc[i][0] - dg * h.x));
        p += fabsf(h.y - dn * (acc[i][1] - dg * h.y));
        p += fabsf(h.z - dn * (acc[i][2] - dg * h.z));
        p += fabsf(h.w - dn * (acc[i][3] - dg * h.w));
        rowred[(r0 + i) * 16 + (tt & 15)] = p;
      }
    }
  }
  if (MODE == 1) {
    __syncthreads();
    if (t < 64) {
      float s = 0.f;
      const float* rowred = smem + 4608;
#pragma unroll
      for (int qq = 0; qq < 16; ++qq) s += rowred[t * 16 + qq];
      atomicAdd(&outp[(size_t)g * n + rt * 64 + t], s);
    }
  }
}

__global__ __launch_bounds__(128) void k_xskew(const float* __restrict__ skew,
    const float* __restrict__ Wsk, const float* __restrict__ bsk, float* __restrict__ g) {
  int b = blockIdx.x, f = threadIdx.x;
  float acc = bsk[f];
  for (int s = 0; s < 64; ++s) acc += skew[b * 64 + s] * Wsk[s * Fd + f];
  g[b * 384 + 256 + f] = fmaxf(acc, 0.f);
}

__global__ __launch_bounds__(128) void k_mlp1(const float* __restrict__ g,
    const float* __restrict__ Wl, const float* __restrict__ bl, float* __restrict__ o) {
  int b = blockIdx.x, f = threadIdx.x;
  float acc = bl[f];
  for (int s = 0; s < 384; ++s) acc += g[b * 384 + s] * Wl[s * 128 + f];
  o[b * 128 + f] = fmaxf(acc, 0.f);
}
__global__ __launch_bounds__(64) void k_mlp2(const float* __restrict__ x,
    const float* __restrict__ Wl, const float* __restrict__ bl, float* __restrict__ o) {
  int b = blockIdx.x, f = threadIdx.x;
  float acc = bl[f];
  for (int s = 0; s < 128; ++s) acc += x[b * 128 + s] * Wl[s * 64 + f];
  o[b * 64 + f] = fmaxf(acc, 0.f);
}
__global__ __launch_bounds__(64) void k_mlp3(const float* __restrict__ x,
    const float* __restrict__ Wl, const float* __restrict__ bl, float* __restrict__ out) {
  int b = blockIdx.x, f = threadIdx.x;
  __shared__ float lg[10];
  if (f < 10) {
    float acc = bl[f];
    for (int s = 0; s < 64; ++s) acc += x[b * 64 + s] * Wl[s * 10 + f];
    lg[f] = acc;
  }
  __syncthreads();
  if (f == 0) {
    float m = lg[0];
    for (int c = 1; c < 10; ++c) m = fmaxf(m, lg[c]);
    float s = 0.f;
    for (int c = 0; c < 10; ++c) s += expf(lg[c] - m);
    float l = logf(s);
    for (int c = 0; c < 10; ++c) out[b * 10 + c] = lg[c] - m - l;
  }
}

extern "C" void kernel_launch(void* const* d_in, const int* in_sizes, int n_in,
                              void* d_out, int out_size, void* d_ws, size_t ws_size,
                              hipStream_t stream) {
  const float* x    = (const float*)d_in[0];
  const int*   src  = (const int*)d_in[1];
  const int*   dst  = (const int*)d_in[2];
  const float* skew = (const float*)d_in[3];
  const float* W1   = (const float*)d_in[4];
  const float* b1   = (const float*)d_in[5];
  const float* W2   = (const float*)d_in[6];
  const float* b2   = (const float*)d_in[7];
  const float* W3   = (const float*)d_in[8];
  const float* b3   = (const float*)d_in[9];
  const float* att1 = (const float*)d_in[10];
  const float* att2 = (const float*)d_in[11];
  const float* Wsk  = (const float*)d_in[12];
  const float* bsk  = (const float*)d_in[13];
  const float* Wl1  = (const float*)d_in[14];
  const float* bl1  = (const float*)d_in[15];
  const float* Wl2  = (const float*)d_in[16];
  const float* bl2  = (const float*)d_in[17];
  const float* Wl3  = (const float*)d_in[18];
  const float* bl3  = (const float*)d_in[19];
  float* out = (float*)d_out;

  char* base = (char*)d_ws;
  size_t off = 0;
  auto alloc = [&](size_t bytes) -> void* {
    void* p = base + off;
    off += (bytes + 255) & ~(size_t)255;
    return p;
  };

  unsigned* adj = (unsigned*)alloc((size_t)Bb * N0 * 32 * 4);        // 8 MB
  float* dis0 = (float*)alloc((size_t)Bb * N0 * 4);
  float* dis1 = (float*)alloc((size_t)Bb * N0 * 4);
  int*   degv = (int*)alloc((size_t)Bb * N0 * 4);
  float* bigA = (float*)alloc((size_t)64 * 1024 * 1024);             // 64 MB multi-use
  float* XW  = bigA;                                                  // [B,1024,128]
  float* h1  = bigA + (size_t)Bb * N0 * Fd;                           // [B,1024,128]
  float* A1  = bigA;                                                  // [B,512,512] (after h1 dead)
  float* XW3 = bigA;                                                  // [B,256,128] (after A1 dead)
  float* h3  = bigA + (size_t)Bb * K2 * Fd;                           // [B,256,128]
  float* score = (float*)alloc((size_t)Bb * N0 * 4);
  float* partial = (float*)alloc((size_t)Bb * N0 * 8 * 4);            // 2 MB
  int*   perm1 = (int*)alloc((size_t)Bb * K1 * 4);
  float* Xp1 = (float*)alloc((size_t)Bb * K1 * Fd * 4);               // later reused as A2
  float* A2  = Xp1;                                                   // [B,256,256] = same bytes
  float* ar1 = (float*)alloc((size_t)Bb * K1 * 4);
  float* ac1 = (float*)alloc((size_t)Bb * K1 * 4);
  float* disc2 = (float*)alloc((size_t)Bb * K1 * 4);
  float* sa2   = (float*)alloc((size_t)Bb * K1 * 4);
  float* disn2 = (float*)alloc((size_t)Bb * K1 * 4);
  float* diag2 = (float*)alloc((size_t)Bb * K1 * 4);
  float* XW2 = (float*)alloc((size_t)Bb * K1 * Fd * 4);               // 16 MB
  float* h2  = (float*)alloc((size_t)Bb * K1 * Fd * 4);               // 16 MB
  int*   perm2 = (int*)alloc((size_t)Bb * K2 * 4);
  float* Xp2 = (float*)alloc((size_t)Bb * K2 * Fd * 4);
  float* ar2 = (float*)alloc((size_t)Bb * K2 * 4);
  float* ac2 = (float*)alloc((size_t)Bb * K2 * 4);
  float* disc3 = (float*)alloc((size_t)Bb * K2 * 4);
  float* sa3   = (float*)alloc((size_t)Bb * K2 * 4);
  float* disn3 = (float*)alloc((size_t)Bb * K2 * 4);
  float* diag3 = (float*)alloc((size_t)Bb * K2 * 4);
  float* g  = (float*)alloc((size_t)Bb * 384 * 4);
  float* t1 = (float*)alloc((size_t)Bb * 128 * 4);
  float* t2 = (float*)alloc((size_t)Bb * 64 * 4);
  // nbr [B*N0][128] u16 = 16 MB; overlays XW2 (dead until stage-2 gemm)
  unsigned short* nbr = (unsigned short*)XW2;
  (void)ws_size; (void)in_sizes; (void)n_in; (void)out_size;

  // stage 1: fused graph build, gemm, LDS-staged conv/nis
  k_graph<<<Bb * 4, 1024, 0, stream>>>(src, dst, adj, nbr, degv, dis0, dis1);
  k_gemm128<<<Bb * N0 / 64, 256, 0, stream>>>(x, W1, XW);
  k_conv1b<<<Bb * 8, 1024, 0, stream>>>(nbr, degv, XW, dis1, b1, h1);
  k_nis1b<<<Bb * 8, 1024, 0, stream>>>(nbr, degv, h1, dis0, partial);
  k_nisred<<<(Bb * N0 + 255) / 256, 256, 0, stream>>>(partial, score, Bb * N0);
  k_topk<<<Bb, N0, 0, stream>>>(score, perm1, N0, K1);
  k_gather<<<Bb * K1, 128, 0, stream>>>(h1, perm1, att1, Xp1, ar1, ac1, N0, K1);
  k_readout<<<Bb, 1024, 0, stream>>>(Xp1, K1, g, 1);
  k_buildA_bit<<<Bb * K1 / 4, 256, 0, stream>>>(adj, perm1, ar1, ac1, A1,
                                                disc2, sa2, disn2, diag2);  // overwrites XW/h1

  // stage 2: dense A1 (fused mm + epilogues, BN=64 x2 col-tiles, split-K x2)
  k_gemm128<<<Bb * K1 / 64, 256, 0, stream>>>(Xp1, W2, XW2);
  k_mmf<0><<<Bb * (K1 / 64) * 2, 512, 0, stream>>>(A1, XW2, disc2, sa2, b2, h2, K1);
  hipMemsetAsync(score, 0, (size_t)Bb * K1 * 4, stream);
  k_mmf<1><<<Bb * (K1 / 64) * 2, 512, 0, stream>>>(A1, h2, disn2, diag2, nullptr, score, K1);
  k_topk<<<Bb, K1, 0, stream>>>(score, perm2, K1, K2);
  k_gather<<<Bb * K2, 128, 0, stream>>>(h2, perm2, att2, Xp2, ar2, ac2, K1, K2);
  k_readout<<<Bb, 1024, 0, stream>>>(Xp2, K2, g, 0);
  k_buildA_dense<<<Bb * K2 / 4, 256, 0, stream>>>(A1, perm2, ar2, ac2, A2,
                                                  disc3, sa3, disn3, diag3);  // overwrites Xp1

  // stage 3: dense A2
  k_gemm128<<<Bb * K2 / 64, 256, 0, stream>>>(Xp2, W3, XW3);           // overwrites A1 region
  k_mmf<0><<<Bb * (K2 / 64) * 2, 512, 0, stream>>>(A2, XW3, disc3, sa3, b3, h3, K2);
  k_readout<<<Bb, 1024, 0, stream>>>(h3, K2, g, 0);

  // head
  k_xskew<<<Bb, 128, 0, stream>>>(skew, Wsk, bsk, g);
  k_mlp1<<<Bb, 128, 0, stream>>>(g, Wl1, bl1, t1);
  k_mlp2<<<Bb, 64, 0, stream>>>(t1, Wl2, bl2, t2);
  k_mlp3<<<Bb, 64, 0, stream>>>(t2, Wl3, bl3, out);
}

// Round 10
// 400.386 us; speedup vs baseline: 1.1711x; 1.1711x over previous
//
#include <hip/hip_runtime.h>
#include <math.h>

#define Bb 64
#define N0 1024
#define NE 16384
#define Fd 128
#define K1 512
#define K2 256
#define RPB 256  // rows per k_graph block

__device__ __forceinline__ float wred_sum(float v) {
#pragma unroll
  for (int o = 32; o > 0; o >>= 1) v += __shfl_down(v, o, 64);
  return v;
}
__device__ __forceinline__ float wred_sum_all(float v) {
#pragma unroll
  for (int o = 32; o > 0; o >>= 1) v += __shfl_xor(v, o, 64);
  return v;
}
__device__ __forceinline__ float wred_max_all(float v) {
#pragma unroll
  for (int o = 32; o > 0; o >>= 1) v = fmaxf(v, __shfl_xor(v, o, 64));
  return v;
}

// ---- fused graph build: edges -> LDS bitmask -> adj + degree + nbr list ----
__global__ __launch_bounds__(1024) void k_graph(const int* __restrict__ src,
    const int* __restrict__ dst, unsigned* __restrict__ adj,
    unsigned short* __restrict__ nbr, int* __restrict__ degv,
    float* __restrict__ dis0, float* __restrict__ dis1) {
  __shared__ unsigned lmask[RPB * 32];  // 32 KB
  int t = threadIdx.x;
  int b = blockIdx.x >> 2;
  int rlo = (blockIdx.x & 3) * RPB;
#pragma unroll
  for (int i = t; i < RPB * 32; i += 1024) lmask[i] = 0;
  __syncthreads();
  const int* sp = src + b * NE;
  const int* dp = dst + b * NE;
#pragma unroll
  for (int e = t; e < NE; e += 1024) {
    int u = sp[e], v = dp[e];
    if (u == v) continue;
    if ((unsigned)(u - rlo) < RPB)
      atomicOr(&lmask[(u - rlo) * 32 + (v >> 5)], 1u << (v & 31));
    if ((unsigned)(v - rlo) < RPB)
      atomicOr(&lmask[(v - rlo) * 32 + (u >> 5)], 1u << (u & 31));
  }
  __syncthreads();
  unsigned* adjg = adj + ((size_t)(b << 10) + rlo) * 32;
#pragma unroll
  for (int i = t; i < RPB * 32; i += 1024) adjg[i] = lmask[i];
  if (t < RPB) {
    int row = (b << 10) + rlo + t;
    const unsigned* wm = &lmask[t * 32];
    int d = 0;
#pragma unroll
    for (int i = 0; i < 32; ++i) d += __popc(wm[i]);
    degv[row] = d;
    dis0[row] = d > 0 ? rsqrtf((float)d) : 0.f;
    dis1[row] = rsqrtf((float)(d + 1));
    unsigned short* dstp = nbr + (size_t)row * 128;
    int o = 0;
#pragma unroll
    for (int w = 0; w < 32; ++w) {
      unsigned m = wm[w];
      int bas = w << 5;
      while (m) { int j = bas + __ffs(m) - 1; m &= m - 1; dstp[o++] = (unsigned short)j; }
    }
  }
}

// ---- C[M,128] = X[M,128] @ W[128,128], M % 64 == 0, grid = M/64, block 256 ----
__global__ __launch_bounds__(256) void k_gemm128(const float* __restrict__ X,
                                                 const float* __restrict__ W,
                                                 float* __restrict__ C) {
  __shared__ float Xs[64][132];
  __shared__ float Ws[32][132];
  int t = threadIdx.x;
  size_t row0 = (size_t)blockIdx.x * 64;
  const float4* Xg = (const float4*)(X + row0 * Fd);
#pragma unroll
  for (int i = 0; i < 8; ++i) {
    int f4 = t + 256 * i;
    float4 v = Xg[f4];
    *(float4*)&Xs[f4 >> 5][(f4 & 31) * 4] = v;
  }
  int r0 = (t >> 5) * 8, c0 = (t & 31) * 4;
  float acc[8][4] = {};
  for (int kb = 0; kb < 128; kb += 32) {
    __syncthreads();
#pragma unroll
    for (int i = 0; i < 4; ++i) {
      int f4 = t + 256 * i;
      float4 v = ((const float4*)(W + (size_t)kb * Fd))[f4];
      *(float4*)&Ws[f4 >> 5][(f4 & 31) * 4] = v;
    }
    __syncthreads();
#pragma unroll
    for (int k = 0; k < 32; ++k) {
      float4 wv = *(const float4*)&Ws[k][c0];
#pragma unroll
      for (int i = 0; i < 8; ++i) {
        float xv = Xs[r0 + i][kb + k];
        acc[i][0] += xv * wv.x; acc[i][1] += xv * wv.y;
        acc[i][2] += xv * wv.z; acc[i][3] += xv * wv.w;
      }
    }
  }
#pragma unroll
  for (int i = 0; i < 8; ++i) {
    float4 o = make_float4(acc[i][0], acc[i][1], acc[i][2], acc[i][3]);
    *(float4*)&C[(row0 + r0 + i) * Fd + c0] = o;
  }
}

// ---- fused conv1 + NIS via LDS-staged source, float4 gathers, XOR slot swizzle ----
// block = (graph, 16-col slice); 1024 threads: c4 = t&3 (4 cols), rsl = t>>2.
__global__ __launch_bounds__(1024) void k_convnis(const unsigned short* __restrict__ nbr,
    const int* __restrict__ degv, const float* __restrict__ XW,
    const float* __restrict__ dis0, const float* __restrict__ dis1,
    const float* __restrict__ b1, float* __restrict__ h1, float* __restrict__ partial) {
  __shared__ float Xs[N0 * 16];  // 64 KB; row r slot s holds logical quad s^((r>>1)&3)
  int t = threadIdx.x;
  int g = blockIdx.x & 63;       // 8 cb-blocks of a graph share an XCD residue
  int cb = blockIdx.x >> 6;
  int c16 = cb * 16;
  const float* XWg = XW + ((size_t)(g << 10)) * Fd + c16;
  const float* d1g = dis1 + (g << 10);
  const float* d0g = dis0 + (g << 10);
  // stage dis1-scaled XW: thread t stages row t (4 swizzled slots)
  {
    int r = t;
    float s = d1g[r];
    int sw = (r >> 1) & 3;
#pragma unroll
    for (int sl = 0; sl < 4; ++sl) {
      int lc = sl ^ sw;
      float4 v = *(const float4*)&XWg[(size_t)r * Fd + lc * 4];
      v.x *= s; v.y *= s; v.z *= s; v.w *= s;
      *(float4*)&Xs[r * 16 + sl * 4] = v;
    }
  }
  __syncthreads();
  int c4 = t & 3, rsl = t >> 2;
  const unsigned short* nb = nbr + (((size_t)(g << 10)) << 7);
  float4 bv = *(const float4*)&b1[c16 + c4 * 4];
  float4 hsave[4];
  int degs[4];
  // phase 2: conv gather
#pragma unroll
  for (int rg = 0; rg < 4; ++rg) {
    int lrow = rg * 256 + rsl;
    int grow = (g << 10) + lrow;
    int deg = degv[grow];
    degs[rg] = deg;
    const unsigned short* nr = nb + ((size_t)lrow << 7);
    float4 acc = make_float4(0.f, 0.f, 0.f, 0.f);
    int dp = deg & ~3, i = 0;
    for (; i < dp; i += 4) {
      unsigned w0 = *(const unsigned*)&nr[i];
      unsigned w1 = *(const unsigned*)&nr[i + 2];
      int jj[4] = {(int)(w0 & 0xffffu), (int)(w0 >> 16),
                   (int)(w1 & 0xffffu), (int)(w1 >> 16)};
      float4 vv[4];
#pragma unroll
      for (int u = 0; u < 4; ++u)
        vv[u] = *(const float4*)&Xs[jj[u] * 16 + ((c4 ^ ((jj[u] >> 1) & 3)) << 2)];
#pragma unroll
      for (int u = 0; u < 4; ++u) {
        acc.x += vv[u].x; acc.y += vv[u].y; acc.z += vv[u].z; acc.w += vv[u].w;
      }
    }
    for (; i < deg; ++i) {
      int j = nr[i];
      float4 v = *(const float4*)&Xs[j * 16 + ((c4 ^ ((j >> 1) & 3)) << 2)];
      acc.x += v.x; acc.y += v.y; acc.z += v.z; acc.w += v.w;
    }
    float di = d1g[lrow];
    float4 self = *(const float4*)&Xs[lrow * 16 + ((c4 ^ ((lrow >> 1) & 3)) << 2)];
    float4 h;
    h.x = fmaxf(di * (acc.x + self.x) + bv.x, 0.f);
    h.y = fmaxf(di * (acc.y + self.y) + bv.y, 0.f);
    h.z = fmaxf(di * (acc.z + self.z) + bv.z, 0.f);
    h.w = fmaxf(di * (acc.w + self.w) + bv.w, 0.f);
    hsave[rg] = h;
    *(float4*)&h1[(size_t)grow * Fd + c16 + c4 * 4] = h;
  }
  __syncthreads();
  // phase 3: restage dis0-scaled h from registers
#pragma unroll
  for (int rg = 0; rg < 4; ++rg) {
    int lrow = rg * 256 + rsl;
    float s0 = d0g[lrow];
    float4 h = hsave[rg];
    h.x *= s0; h.y *= s0; h.z *= s0; h.w *= s0;
    *(float4*)&Xs[lrow * 16 + ((c4 ^ ((lrow >> 1) & 3)) << 2)] = h;
  }
  __syncthreads();
  // phase 4: NIS gather
#pragma unroll
  for (int rg = 0; rg < 4; ++rg) {
    int lrow = rg * 256 + rsl;
    int grow = (g << 10) + lrow;
    int deg = degs[rg];
    const unsigned short* nr = nb + ((size_t)lrow << 7);
    float4 acc = make_float4(0.f, 0.f, 0.f, 0.f);
    int dp = deg & ~3, i = 0;
    for (; i < dp; i += 4) {
      unsigned w0 = *(const unsigned*)&nr[i];
      unsigned w1 = *(const unsigned*)&nr[i + 2];
      int jj[4] = {(int)(w0 & 0xffffu), (int)(w0 >> 16),
                   (int)(w1 & 0xffffu), (int)(w1 >> 16)};
      float4 vv[4];
#pragma unroll
      for (int u = 0; u < 4; ++u)
        vv[u] = *(const float4*)&Xs[jj[u] * 16 + ((c4 ^ ((jj[u] >> 1) & 3)) << 2)];
#pragma unroll
      for (int u = 0; u < 4; ++u) {
        acc.x += vv[u].x; acc.y += vv[u].y; acc.z += vv[u].z; acc.w += vv[u].w;
      }
    }
    for (; i < deg; ++i) {
      int j = nr[i];
      float4 v = *(const float4*)&Xs[j * 16 + ((c4 ^ ((j >> 1) & 3)) << 2)];
      acc.x += v.x; acc.y += v.y; acc.z += v.z; acc.w += v.w;
    }
    float d0 = d0g[lrow];
    float4 h = hsave[rg];
    float p = fabsf(h.x - d0 * acc.x) + fabsf(h.y - d0 * acc.y) +
              fabsf(h.z - d0 * acc.z) + fabsf(h.w - d0 * acc.w);
    p += __shfl_xor(p, 1, 64);
    p += __shfl_xor(p, 2, 64);
    if (c4 == 0) partial[(size_t)grow * 8 + cb] = p;
  }
}

__global__ void k_nisred(const float* __restrict__ partial, float* __restrict__ score,
                         int total) {
  int row = blockIdx.x * 256 + threadIdx.x;
  if (row >= total) return;
  float4 a = *(const float4*)&partial[(size_t)row * 8];
  float4 b = *(const float4*)&partial[(size_t)row * 8 + 4];
  score[row] = a.x + a.y + a.z + a.w + b.x + b.y + b.z + b.w;
}

// ---- exact top-k per graph: bitonic sort of (score,idx) packed u64 keys ----
__global__ __launch_bounds__(1024) void k_topk(const float* __restrict__ score,
                                               int* __restrict__ perm, int n, int k) {
  __shared__ unsigned long long keys[1024];
  int b = blockIdx.x, t = threadIdx.x;
  float s = score[b * n + t];
  unsigned ub = __float_as_uint(s);
  unsigned su = (ub & 0x80000000u) ? ~ub : (ub | 0x80000000u);  // monotone map
  keys[t] = ((unsigned long long)(~su) << 32) | (unsigned)t;    // asc sort = desc score, asc idx
  __syncthreads();
  for (int kk = 2; kk <= n; kk <<= 1) {
    for (int j = kk >> 1; j > 0; j >>= 1) {
      int ixj = t ^ j;
      if (ixj > t) {
        unsigned long long a = keys[t], c = keys[ixj];
        bool up = ((t & kk) == 0);
        if ((a > c) == up) { keys[t] = c; keys[ixj] = a; }
      }
      __syncthreads();
    }
  }
  if (t < k) perm[b * k + t] = (int)(keys[t] & 0xffffffffu);
}

// ---- gather pooled rows + attention dots ----
__global__ __launch_bounds__(128) void k_gather(const float* __restrict__ h,
    const int* __restrict__ perm, const float* __restrict__ att, float* __restrict__ Xp,
    float* __restrict__ ar, float* __restrict__ ac, int n, int k) {
  int idx = blockIdx.x, f = threadIdx.x;
  int b = idx / k;
  __shared__ float red[4];
  int p = perm[idx];
  float v = h[((size_t)b * n + p) * Fd + f];
  Xp[(size_t)idx * Fd + f] = v;
  float r1 = wred_sum(v * att[f]);
  float r2 = wred_sum(v * att[Fd + f]);
  if ((f & 63) == 0) { red[f >> 6] = r1; red[2 + (f >> 6)] = r2; }
  __syncthreads();
  if (f == 0) { ar[idx] = red[0] + red[1]; ac[idx] = red[2] + red[3]; }
}

// ---- readout: g[b][0:128] (+)= relu(max), g[b][128:256] (+)= relu(mean) ----
__global__ __launch_bounds__(1024) void k_readout(const float* __restrict__ X, int n,
                                                  float* __restrict__ g, int init) {
  int b = blockIdx.x, t = threadIdx.x;
  int f = t & 127, rs = t >> 7;
  __shared__ float smax[8][128];
  __shared__ float ssum[8][128];
  int per = n >> 3;
  const float* Xs = X + ((size_t)b * n + (size_t)rs * per) * Fd + f;
  float mx = -3.0e38f, sm = 0.f;
  for (int j = 0; j < per; j += 8) {
    float vv[8];
#pragma unroll
    for (int u = 0; u < 8; ++u) vv[u] = Xs[(size_t)(j + u) * Fd];
#pragma unroll
    for (int u = 0; u < 8; ++u) { mx = fmaxf(mx, vv[u]); sm += vv[u]; }
  }
  smax[rs][f] = mx; ssum[rs][f] = sm;
  __syncthreads();
  if (t < 128) {
    float m = smax[0][f], s = ssum[0][f];
#pragma unroll
    for (int q = 1; q < 8; ++q) { m = fmaxf(m, smax[q][f]); s += ssum[q][f]; }
    float a = fmaxf(m, 0.f);
    float m2 = fmaxf(s / (float)n, 0.f);
    if (init) { g[b * 384 + f] = a; g[b * 384 + 128 + f] = m2; }
    else      { g[b * 384 + f] += a; g[b * 384 + 128 + f] += m2; }
  }
}

// ---- A1 = softmax_row(leakyrelu(ar_i+ac_j) + bit(pi,pj)) + row stats ----
__global__ __launch_bounds__(256) void k_buildA_bit(const unsigned* __restrict__ adj,
    const int* __restrict__ perm, const float* __restrict__ ar, const float* __restrict__ ac,
    float* __restrict__ A, float* __restrict__ disc, float* __restrict__ saO,
    float* __restrict__ disn, float* __restrict__ diagO) {
  int wid = threadIdx.x >> 6, lane = threadIdx.x & 63;
  int row = blockIdx.x * 4 + wid;      // [0, Bb*K1)
  int b = row >> 9, i = row & (K1 - 1);
  int pbase = b << 9;
  int pi = perm[pbase + i];
  float ari = ar[pbase + i];
  int j0 = lane * 8;
  float acv[8]; int pj[8];
  *(float4*)&acv[0] = *(const float4*)&ac[pbase + j0];
  *(float4*)&acv[4] = *(const float4*)&ac[pbase + j0 + 4];
  *(int4*)&pj[0] = *(const int4*)&perm[pbase + j0];
  *(int4*)&pj[4] = *(const int4*)&perm[pbase + j0 + 4];
  const unsigned* arow = adj + (size_t)((b << 10) + pi) * 32;
  float xv[8];
#pragma unroll
  for (int u = 0; u < 8; ++u) {
    float x = ari + acv[u];
    x = x > 0.f ? x : 0.2f * x;
    unsigned word = arow[pj[u] >> 5];
    xv[u] = x + (float)((word >> (pj[u] & 31)) & 1u);
  }
  float m = xv[0];
#pragma unroll
  for (int u = 1; u < 8; ++u) m = fmaxf(m, xv[u]);
  m = wred_max_all(m);
  float e[8], ls = 0.f;
#pragma unroll
  for (int u = 0; u < 8; ++u) { e[u] = expf(xv[u] - m); ls += e[u]; }
  float s = wred_sum_all(ls);
  float inv = 1.0f / s;
  float av[8]; float lsum = 0.f;
#pragma unroll
  for (int u = 0; u < 8; ++u) { av[u] = e[u] * inv; lsum += av[u]; }
  float* Ar = A + (size_t)row * K1 + j0;
  *(float4*)&Ar[0] = make_float4(av[0], av[1], av[2], av[3]);
  *(float4*)&Ar[4] = make_float4(av[4], av[5], av[6], av[7]);
  float rs = wred_sum_all(lsum);
  float dsel = av[i & 7];                 // uniform index
  float dval = __shfl(dsel, i >> 3, 64);
  if (lane == 0) {
    float sav = (dval == 0.f) ? 1.f : 0.f;
    float deg = rs + sav;
    disc[row] = deg > 0.f ? rsqrtf(deg) : 0.f;
    saO[row] = sav;
    float deg0 = rs - dval;
    disn[row] = deg0 > 0.f ? rsqrtf(deg0) : 0.f;
    diagO[row] = dval;
  }
}

// ---- A2 = softmax_row(leakyrelu(ar_i+ac_j) + A1[pi,pj]) + row stats ----
__global__ __launch_bounds__(256) void k_buildA_dense(const float* __restrict__ Aprev,
    const int* __restrict__ perm, const float* __restrict__ ar, const float* __restrict__ ac,
    float* __restrict__ A, float* __restrict__ disc, float* __restrict__ saO,
    float* __restrict__ disn, float* __restrict__ diagO) {
  int wid = threadIdx.x >> 6, lane = threadIdx.x & 63;
  int row = blockIdx.x * 4 + wid;      // [0, Bb*K2)
  int b = row >> 8, i = row & (K2 - 1);
  int pbase = b << 8;
  int pi = perm[pbase + i];
  float ari = ar[pbase + i];
  int j0 = lane * 4;
  float acv[4]; int pj[4];
  *(float4*)&acv[0] = *(const float4*)&ac[pbase + j0];
  *(int4*)&pj[0] = *(const int4*)&perm[pbase + j0];
  const float* aprow = Aprev + (size_t)((b << 9) + pi) * K1;
  float xv[4];
#pragma unroll
  for (int u = 0; u < 4; ++u) {
    float x = ari + acv[u];
    x = x > 0.f ? x : 0.2f * x;
    xv[u] = x + aprow[pj[u]];
  }
  float m = fmaxf(fmaxf(xv[0], xv[1]), fmaxf(xv[2], xv[3]));
  m = wred_max_all(m);
  float e[4], ls = 0.f;
#pragma unroll
  for (int u = 0; u < 4; ++u) { e[u] = expf(xv[u] - m); ls += e[u]; }
  float s = wred_sum_all(ls);
  float inv = 1.0f / s;
  float av[4]; float lsum = 0.f;
#pragma unroll
  for (int u = 0; u < 4; ++u) { av[u] = e[u] * inv; lsum += av[u]; }
  *(float4*)&A[(size_t)row * K2 + j0] = make_float4(av[0], av[1], av[2], av[3]);
  float rs = wred_sum_all(lsum);
  float dsel = av[i & 3];
  float dval = __shfl(dsel, i >> 2, 64);
  if (lane == 0) {
    float sav = (dval == 0.f) ? 1.f : 0.f;
    float deg = rs + sav;
    disc[row] = deg > 0.f ? rsqrtf(deg) : 0.f;
    saO[row] = sav;
    float deg0 = rs - dval;
    disn[row] = deg0 > 0.f ? rsqrtf(deg0) : 0.f;
    diagO[row] = dval;
  }
}

// ---- fused dense mm: out = epilogue(A[b] @ diag(wrow) Y[b]) ----
// BM=64, BN=64 (2 col-tiles), split-K x2 (512 threads).
template <int MODE>
__global__ __launch_bounds__(512) void k_mmf(const float* __restrict__ A,
    const float* __restrict__ Y, const float* __restrict__ wrow,
    const float* __restrict__ aux, const float* __restrict__ bias,
    float* __restrict__ outp, int n) {
  __shared__ float smem[8960];  // As[2][64][36] @0 (4608), Ys[2][32][68] @4608 (4352)
  int t = threadIdx.x;
  int kg = t >> 8, tt = t & 255;
  int tiles2 = (n >> 6) << 1;    // row-tiles * 2 col-tiles
  int bid = blockIdx.x;
  int c = bid & 7, q = bid >> 3;
  int g = c * 8 + q / tiles2;    // graph (8 graphs per XCD)
  int rem = q % tiles2;
  int rt = rem >> 1, ct = rem & 1;
  const float* Ab = A + (size_t)g * n * n + (size_t)(rt * 64) * n;
  const float* Yb = Y + (size_t)g * n * Fd + ct * 64;
  const float* wb = wrow + (size_t)g * n;
  int r0 = (tt >> 4) * 4, c0 = (tt & 15) * 4;
  float acc[4][4] = {};
  int kbase = kg * (n >> 1);
  float* Asg = smem + kg * 2304;
  float* Ysg = smem + 4608 + kg * 2176;
  for (int kb = 0; kb < (n >> 1); kb += 32) {
    int kglob = kbase + kb;
    __syncthreads();
#pragma unroll
    for (int ii = 0; ii < 2; ++ii) {
      int f4 = tt + 256 * ii;
      int r = f4 >> 3, c4 = (f4 & 7) * 4;
      *(float4*)&Asg[r * 36 + c4] = *(const float4*)&Ab[(size_t)r * n + kglob + c4];
    }
#pragma unroll
    for (int ii = 0; ii < 2; ++ii) {
      int f4 = tt + 256 * ii;
      int r = f4 >> 4, c4 = (f4 & 15) * 4;
      float4 v = *(const float4*)&Yb[(size_t)(kglob + r) * Fd + c4];
      float sc = wb[kglob + r];
      v.x *= sc; v.y *= sc; v.z *= sc; v.w *= sc;
      *(float4*)&Ysg[r * 68 + c4] = v;
    }
    __syncthreads();
#pragma unroll
    for (int k4 = 0; k4 < 8; ++k4) {
      float a_[4][4];
#pragma unroll
      for (int i = 0; i < 4; ++i)
        *(float4*)a_[i] = *(const float4*)&Asg[(r0 + i) * 36 + k4 * 4];
#pragma unroll
      for (int kk = 0; kk < 4; ++kk) {
        float4 y = *(const float4*)&Ysg[(k4 * 4 + kk) * 68 + c0];
#pragma unroll
        for (int i = 0; i < 4; ++i) {
          float av = a_[i][kk];
          acc[i][0] += av * y.x; acc[i][1] += av * y.y;
          acc[i][2] += av * y.z; acc[i][3] += av * y.w;
        }
      }
    }
  }
  float* mrg = smem;
  __syncthreads();
  if (kg == 1) {
#pragma unroll
    for (int i = 0; i < 4; ++i)
      *(float4*)&mrg[(r0 + i) * 64 + c0] = *(float4*)&acc[i][0];
  }
  __syncthreads();
  if (kg == 0) {
#pragma unroll
    for (int i = 0; i < 4; ++i) {
      float4 m0 = *(float4*)&mrg[(r0 + i) * 64 + c0];
      acc[i][0] += m0.x; acc[i][1] += m0.y; acc[i][2] += m0.z; acc[i][3] += m0.w;
    }
    if (MODE == 0) {
      float4 bv = *(const float4*)&bias[ct * 64 + c0];
#pragma unroll
      for (int i = 0; i < 4; ++i) {
        int rl = rt * 64 + r0 + i;
        size_t R = (size_t)g * n + rl;
        float dc = wb[rl];
        float sv = aux[R] * dc;
        float4 y = *(const float4*)&Y[R * Fd + ct * 64 + c0];
        float4 o;
        o.x = fmaxf(dc * (acc[i][0] + sv * y.x) + bv.x, 0.f);
        o.y = fmaxf(dc * (acc[i][1] + sv * y.y) + bv.y, 0.f);
        o.z = fmaxf(dc * (acc[i][2] + sv * y.z) + bv.z, 0.f);
        o.w = fmaxf(dc * (acc[i][3] + sv * y.w) + bv.w, 0.f);
        *(float4*)&outp[R * Fd + ct * 64 + c0] = o;
      }
    } else {
      float* rowred = smem + 4608;  // Ys region dead; [64][16]
#pragma unroll
      for (int i = 0; i < 4; ++i) {
        int rl = rt * 64 + r0 + i;
        size_t R = (size_t)g * n + rl;
        float dn = wb[rl];
        float dg = aux[R] * dn;
        float4 h = *(const float4*)&Y[R * Fd + ct * 64 + c0];
        float p = 0.f;
        p += fabsf(h.x - dn * (acc[i][0] - dg * h.x));
        p += fabsf(h.y - dn * (acc[i][1] - dg * h.y));
        p += fabsf(h.z - dn * (acc[i][2] - dg * h.z));
        p += fabsf(h.w - dn * (acc[i][3] - dg * h.w));
        rowred[(r0 + i) * 16 + (tt & 15)] = p;
      }
    }
  }
  if (MODE == 1) {
    __syncthreads();
    if (t < 64) {
      float s = 0.f;
      const float* rowred = smem + 4608;
#pragma unroll
      for (int qq = 0; qq < 16; ++qq) s += rowred[t * 16 + qq];
      atomicAdd(&outp[(size_t)g * n + rt * 64 + t], s);
    }
  }
}

__global__ __launch_bounds__(128) void k_xskew(const float* __restrict__ skew,
    const float* __restrict__ Wsk, const float* __restrict__ bsk, float* __restrict__ g) {
  int b = blockIdx.x, f = threadIdx.x;
  float acc = bsk[f];
  for (int s = 0; s < 64; ++s) acc += skew[b * 64 + s] * Wsk[s * Fd + f];
  g[b * 384 + 256 + f] = fmaxf(acc, 0.f);
}

__global__ __launch_bounds__(128) void k_mlp1(const float* __restrict__ g,
    const float* __restrict__ Wl, const float* __restrict__ bl, float* __restrict__ o) {
  int b = blockIdx.x, f = threadIdx.x;
  float acc = bl[f];
  for (int s = 0; s < 384; ++s) acc += g[b * 384 + s] * Wl[s * 128 + f];
  o[b * 128 + f] = fmaxf(acc, 0.f);
}
__global__ __launch_bounds__(64) void k_mlp2(const float* __restrict__ x,
    const float* __restrict__ Wl, const float* __restrict__ bl, float* __restrict__ o) {
  int b = blockIdx.x, f = threadIdx.x;
  float acc = bl[f];
  for (int s = 0; s < 128; ++s) acc += x[b * 128 + s] * Wl[s * 64 + f];
  o[b * 64 + f] = fmaxf(acc, 0.f);
}
__global__ __launch_bounds__(64) void k_mlp3(const float* __restrict__ x,
    const float* __restrict__ Wl, const float* __restrict__ bl, float* __restrict__ out) {
  int b = blockIdx.x, f = threadIdx.x;
  __shared__ float lg[10];
  if (f < 10) {
    float acc = bl[f];
    for (int s = 0; s < 64; ++s) acc += x[b * 64 + s] * Wl[s * 10 + f];
    lg[f] = acc;
  }
  __syncthreads();
  if (f == 0) {
    float m = lg[0];
    for (int c = 1; c < 10; ++c) m = fmaxf(m, lg[c]);
    float s = 0.f;
    for (int c = 0; c < 10; ++c) s += expf(lg[c] - m);
    float l = logf(s);
    for (int c = 0; c < 10; ++c) out[b * 10 + c] = lg[c] - m - l;
  }
}

extern "C" void kernel_launch(void* const* d_in, const int* in_sizes, int n_in,
                              void* d_out, int out_size, void* d_ws, size_t ws_size,
                              hipStream_t stream) {
  const float* x    = (const float*)d_in[0];
  const int*   src  = (const int*)d_in[1];
  const int*   dst  = (const int*)d_in[2];
  const float* skew = (const float*)d_in[3];
  const float* W1   = (const float*)d_in[4];
  const float* b1   = (const float*)d_in[5];
  const float* W2   = (const float*)d_in[6];
  const float* b2   = (const float*)d_in[7];
  const float* W3   = (const float*)d_in[8];
  const float* b3   = (const float*)d_in[9];
  const float* att1 = (const float*)d_in[10];
  const float* att2 = (const float*)d_in[11];
  const float* Wsk  = (const float*)d_in[12];
  const float* bsk  = (const float*)d_in[13];
  const float* Wl1  = (const float*)d_in[14];
  const float* bl1  = (const float*)d_in[15];
  const float* Wl2  = (const float*)d_in[16];
  const float* bl2  = (const float*)d_in[17];
  const float* Wl3  = (const float*)d_in[18];
  const float* bl3  = (const float*)d_in[19];
  float* out = (float*)d_out;

  char* base = (char*)d_ws;
  size_t off = 0;
  auto alloc = [&](size_t bytes) -> void* {
    void* p = base + off;
    off += (bytes + 255) & ~(size_t)255;
    return p;
  };

  unsigned* adj = (unsigned*)alloc((size_t)Bb * N0 * 32 * 4);        // 8 MB
  float* dis0 = (float*)alloc((size_t)Bb * N0 * 4);
  float* dis1 = (float*)alloc((size_t)Bb * N0 * 4);
  int*   degv = (int*)alloc((size_t)Bb * N0 * 4);
  float* bigA = (float*)alloc((size_t)64 * 1024 * 1024);             // 64 MB multi-use
  float* XW  = bigA;                                                  // [B,1024,128]
  float* h1  = bigA + (size_t)Bb * N0 * Fd;                           // [B,1024,128]
  float* A1  = bigA;                                                  // [B,512,512] (after h1 dead)
  float* XW3 = bigA;                                                  // [B,256,128] (after A1 dead)
  float* h3  = bigA + (size_t)Bb * K2 * Fd;                           // [B,256,128]
  float* score = (float*)alloc((size_t)Bb * N0 * 4);
  float* partial = (float*)alloc((size_t)Bb * N0 * 8 * 4);            // 2 MB
  int*   perm1 = (int*)alloc((size_t)Bb * K1 * 4);
  float* Xp1 = (float*)alloc((size_t)Bb * K1 * Fd * 4);               // later reused as A2
  float* A2  = Xp1;                                                   // [B,256,256] = same bytes
  float* ar1 = (float*)alloc((size_t)Bb * K1 * 4);
  float* ac1 = (float*)alloc((size_t)Bb * K1 * 4);
  float* disc2 = (float*)alloc((size_t)Bb * K1 * 4);
  float* sa2   = (float*)alloc((size_t)Bb * K1 * 4);
  float* disn2 = (float*)alloc((size_t)Bb * K1 * 4);
  float* diag2 = (float*)alloc((size_t)Bb * K1 * 4);
  float* XW2 = (float*)alloc((size_t)Bb * K1 * Fd * 4);               // 16 MB
  float* h2  = (float*)alloc((size_t)Bb * K1 * Fd * 4);               // 16 MB
  int*   perm2 = (int*)alloc((size_t)Bb * K2 * 4);
  float* Xp2 = (float*)alloc((size_t)Bb * K2 * Fd * 4);
  float* ar2 = (float*)alloc((size_t)Bb * K2 * 4);
  float* ac2 = (float*)alloc((size_t)Bb * K2 * 4);
  float* disc3 = (float*)alloc((size_t)Bb * K2 * 4);
  float* sa3   = (float*)alloc((size_t)Bb * K2 * 4);
  float* disn3 = (float*)alloc((size_t)Bb * K2 * 4);
  float* diag3 = (float*)alloc((size_t)Bb * K2 * 4);
  float* g  = (float*)alloc((size_t)Bb * 384 * 4);
  float* t1 = (float*)alloc((size_t)Bb * 128 * 4);
  float* t2 = (float*)alloc((size_t)Bb * 64 * 4);
  // nbr [B*N0][128] u16 = 16 MB; overlays XW2 (dead until stage-2 gemm)
  unsigned short* nbr = (unsigned short*)XW2;
  (void)ws_size; (void)in_sizes; (void)n_in; (void)out_size;

  // stage 1: fused graph build, gemm, fused conv+nis (LDS-staged, float4 gathers)
  k_graph<<<Bb * 4, 1024, 0, stream>>>(src, dst, adj, nbr, degv, dis0, dis1);
  k_gemm128<<<Bb * N0 / 64, 256, 0, stream>>>(x, W1, XW);
  k_convnis<<<Bb * 8, 1024, 0, stream>>>(nbr, degv, XW, dis0, dis1, b1, h1, partial);
  k_nisred<<<(Bb * N0 + 255) / 256, 256, 0, stream>>>(partial, score, Bb * N0);
  k_topk<<<Bb, N0, 0, stream>>>(score, perm1, N0, K1);
  k_gather<<<Bb * K1, 128, 0, stream>>>(h1, perm1, att1, Xp1, ar1, ac1, N0, K1);
  k_readout<<<Bb, 1024, 0, stream>>>(Xp1, K1, g, 1);
  k_buildA_bit<<<Bb * K1 / 4, 256, 0, stream>>>(adj, perm1, ar1, ac1, A1,
                                                disc2, sa2, disn2, diag2);  // overwrites XW/h1

  // stage 2: dense A1 (fused mm + epilogues, BN=64 x2 col-tiles, split-K x2)
  k_gemm128<<<Bb * K1 / 64, 256, 0, stream>>>(Xp1, W2, XW2);
  k_mmf<0><<<Bb * (K1 / 64) * 2, 512, 0, stream>>>(A1, XW2, disc2, sa2, b2, h2, K1);
  hipMemsetAsync(score, 0, (size_t)Bb * K1 * 4, stream);
  k_mmf<1><<<Bb * (K1 / 64) * 2, 512, 0, stream>>>(A1, h2, disn2, diag2, nullptr, score, K1);
  k_topk<<<Bb, K1, 0, stream>>>(score, perm2, K1, K2);
  k_gather<<<Bb * K2, 128, 0, stream>>>(h2, perm2, att2, Xp2, ar2, ac2, K1, K2);
  k_readout<<<Bb, 1024, 0, stream>>>(Xp2, K2, g, 0);
  k_buildA_dense<<<Bb * K2 / 4, 256, 0, stream>>>(A1, perm2, ar2, ac2, A2,
                                                  disc3, sa3, disn3, diag3);  // overwrites Xp1

  // stage 3: dense A2
  k_gemm128<<<Bb * K2 / 64, 256, 0, stream>>>(Xp2, W3, XW3);           // overwrites A1 region
  k_mmf<0><<<Bb * (K2 / 64) * 2, 512, 0, stream>>>(A2, XW3, disc3, sa3, b3, h3, K2);
  k_readout<<<Bb, 1024, 0, stream>>>(h3, K2, g, 0);

  // head
  k_xskew<<<Bb, 128, 0, stream>>>(skew, Wsk, bsk, g);
  k_mlp1<<<Bb, 128, 0, stream>>>(g, Wl1, bl1, t1);
  k_mlp2<<<Bb, 64, 0, stream>>>(t1, Wl2, bl2, t2);
  k_mlp3<<<Bb, 64, 0, stream>>>(t2, Wl3, bl3, out);
}

// Round 11
// 392.279 us; speedup vs baseline: 1.1953x; 1.0207x over previous
//
#include <hip/hip_runtime.h>
#include <math.h>

#define Bb 64
#define N0 1024
#define NE 16384
#define Fd 128
#define K1 512
#define K2 256
#define RPB 256  // rows per k_graph block

typedef __attribute__((ext_vector_type(8))) short short8v;
typedef __attribute__((ext_vector_type(4))) float float4v;

__device__ __forceinline__ float wred_sum(float v) {
#pragma unroll
  for (int o = 32; o > 0; o >>= 1) v += __shfl_down(v, o, 64);
  return v;
}
__device__ __forceinline__ float wred_sum_all(float v) {
#pragma unroll
  for (int o = 32; o > 0; o >>= 1) v += __shfl_xor(v, o, 64);
  return v;
}
__device__ __forceinline__ float wred_max_all(float v) {
#pragma unroll
  for (int o = 32; o > 0; o >>= 1) v = fmaxf(v, __shfl_xor(v, o, 64));
  return v;
}
__device__ __forceinline__ unsigned short bf16hi(float x) {
  unsigned u = __float_as_uint(x);
  return (unsigned short)((u + 0x7fffu + ((u >> 16) & 1u)) >> 16);
}

// ---- fused graph build: edges -> LDS bitmask -> adj + degree + nbr list ----
__global__ __launch_bounds__(1024) void k_graph(const int* __restrict__ src,
    const int* __restrict__ dst, unsigned* __restrict__ adj,
    unsigned short* __restrict__ nbr, int* __restrict__ degv,
    float* __restrict__ dis0, float* __restrict__ dis1) {
  __shared__ unsigned lmask[RPB * 32];  // 32 KB
  int t = threadIdx.x;
  int b = blockIdx.x >> 2;
  int rlo = (blockIdx.x & 3) * RPB;
#pragma unroll
  for (int i = t; i < RPB * 32; i += 1024) lmask[i] = 0;
  __syncthreads();
  const int* sp = src + b * NE;
  const int* dp = dst + b * NE;
#pragma unroll
  for (int e = t; e < NE; e += 1024) {
    int u = sp[e], v = dp[e];
    if (u == v) continue;
    if ((unsigned)(u - rlo) < RPB)
      atomicOr(&lmask[(u - rlo) * 32 + (v >> 5)], 1u << (v & 31));
    if ((unsigned)(v - rlo) < RPB)
      atomicOr(&lmask[(v - rlo) * 32 + (u >> 5)], 1u << (u & 31));
  }
  __syncthreads();
  unsigned* adjg = adj + ((size_t)(b << 10) + rlo) * 32;
#pragma unroll
  for (int i = t; i < RPB * 32; i += 1024) adjg[i] = lmask[i];
  if (t < RPB) {
    int row = (b << 10) + rlo + t;
    const unsigned* wm = &lmask[t * 32];
    int d = 0;
#pragma unroll
    for (int i = 0; i < 32; ++i) d += __popc(wm[i]);
    degv[row] = d;
    dis0[row] = d > 0 ? rsqrtf((float)d) : 0.f;
    dis1[row] = rsqrtf((float)(d + 1));
    unsigned short* dstp = nbr + (size_t)row * 128;
    int o = 0;
#pragma unroll
    for (int w = 0; w < 32; ++w) {
      unsigned m = wm[w];
      int bas = w << 5;
      while (m) { int j = bas + __ffs(m) - 1; m &= m - 1; dstp[o++] = (unsigned short)j; }
    }
  }
}

// ---- C[M,128] = X[M,128] @ W[128,128], M % 64 == 0, grid = M/64, block 256 ----
__global__ __launch_bounds__(256) void k_gemm128(const float* __restrict__ X,
                                                 const float* __restrict__ W,
                                                 float* __restrict__ C) {
  __shared__ float Xs[64][132];
  __shared__ float Ws[32][132];
  int t = threadIdx.x;
  size_t row0 = (size_t)blockIdx.x * 64;
  const float4* Xg = (const float4*)(X + row0 * Fd);
#pragma unroll
  for (int i = 0; i < 8; ++i) {
    int f4 = t + 256 * i;
    float4 v = Xg[f4];
    *(float4*)&Xs[f4 >> 5][(f4 & 31) * 4] = v;
  }
  int r0 = (t >> 5) * 8, c0 = (t & 31) * 4;
  float acc[8][4] = {};
  for (int kb = 0; kb < 128; kb += 32) {
    __syncthreads();
#pragma unroll
    for (int i = 0; i < 4; ++i) {
      int f4 = t + 256 * i;
      float4 v = ((const float4*)(W + (size_t)kb * Fd))[f4];
      *(float4*)&Ws[f4 >> 5][(f4 & 31) * 4] = v;
    }
    __syncthreads();
#pragma unroll
    for (int k = 0; k < 32; ++k) {
      float4 wv = *(const float4*)&Ws[k][c0];
#pragma unroll
      for (int i = 0; i < 8; ++i) {
        float xv = Xs[r0 + i][kb + k];
        acc[i][0] += xv * wv.x; acc[i][1] += xv * wv.y;
        acc[i][2] += xv * wv.z; acc[i][3] += xv * wv.w;
      }
    }
  }
#pragma unroll
  for (int i = 0; i < 8; ++i) {
    float4 o = make_float4(acc[i][0], acc[i][1], acc[i][2], acc[i][3]);
    *(float4*)&C[(row0 + r0 + i) * Fd + c0] = o;
  }
}

// ---- fused conv1 + NIS via LDS-staged source, float4 gathers, XOR slot swizzle ----
__global__ __launch_bounds__(1024) void k_convnis(const unsigned short* __restrict__ nbr,
    const int* __restrict__ degv, const float* __restrict__ XW,
    const float* __restrict__ dis0, const float* __restrict__ dis1,
    const float* __restrict__ b1, float* __restrict__ h1, float* __restrict__ partial) {
  __shared__ float Xs[N0 * 16];  // 64 KB; row r slot s holds logical quad s^((r>>1)&3)
  int t = threadIdx.x;
  int g = blockIdx.x & 63;
  int cb = blockIdx.x >> 6;
  int c16 = cb * 16;
  const float* XWg = XW + ((size_t)(g << 10)) * Fd + c16;
  const float* d1g = dis1 + (g << 10);
  const float* d0g = dis0 + (g << 10);
  {
    int r = t;
    float s = d1g[r];
    int sw = (r >> 1) & 3;
#pragma unroll
    for (int sl = 0; sl < 4; ++sl) {
      int lc = sl ^ sw;
      float4 v = *(const float4*)&XWg[(size_t)r * Fd + lc * 4];
      v.x *= s; v.y *= s; v.z *= s; v.w *= s;
      *(float4*)&Xs[r * 16 + sl * 4] = v;
    }
  }
  __syncthreads();
  int c4 = t & 3, rsl = t >> 2;
  const unsigned short* nb = nbr + (((size_t)(g << 10)) << 7);
  float4 bv = *(const float4*)&b1[c16 + c4 * 4];
  float4 hsave[4];
  int degs[4];
#pragma unroll
  for (int rg = 0; rg < 4; ++rg) {
    int lrow = rg * 256 + rsl;
    int grow = (g << 10) + lrow;
    int deg = degv[grow];
    degs[rg] = deg;
    const unsigned short* nr = nb + ((size_t)lrow << 7);
    float4 acc = make_float4(0.f, 0.f, 0.f, 0.f);
    int dp = deg & ~3, i = 0;
    for (; i < dp; i += 4) {
      unsigned w0 = *(const unsigned*)&nr[i];
      unsigned w1 = *(const unsigned*)&nr[i + 2];
      int jj[4] = {(int)(w0 & 0xffffu), (int)(w0 >> 16),
                   (int)(w1 & 0xffffu), (int)(w1 >> 16)};
      float4 vv[4];
#pragma unroll
      for (int u = 0; u < 4; ++u)
        vv[u] = *(const float4*)&Xs[jj[u] * 16 + ((c4 ^ ((jj[u] >> 1) & 3)) << 2)];
#pragma unroll
      for (int u = 0; u < 4; ++u) {
        acc.x += vv[u].x; acc.y += vv[u].y; acc.z += vv[u].z; acc.w += vv[u].w;
      }
    }
    for (; i < deg; ++i) {
      int j = nr[i];
      float4 v = *(const float4*)&Xs[j * 16 + ((c4 ^ ((j >> 1) & 3)) << 2)];
      acc.x += v.x; acc.y += v.y; acc.z += v.z; acc.w += v.w;
    }
    float di = d1g[lrow];
    float4 self = *(const float4*)&Xs[lrow * 16 + ((c4 ^ ((lrow >> 1) & 3)) << 2)];
    float4 h;
    h.x = fmaxf(di * (acc.x + self.x) + bv.x, 0.f);
    h.y = fmaxf(di * (acc.y + self.y) + bv.y, 0.f);
    h.z = fmaxf(di * (acc.z + self.z) + bv.z, 0.f);
    h.w = fmaxf(di * (acc.w + self.w) + bv.w, 0.f);
    hsave[rg] = h;
    *(float4*)&h1[(size_t)grow * Fd + c16 + c4 * 4] = h;
  }
  __syncthreads();
#pragma unroll
  for (int rg = 0; rg < 4; ++rg) {
    int lrow = rg * 256 + rsl;
    float s0 = d0g[lrow];
    float4 h = hsave[rg];
    h.x *= s0; h.y *= s0; h.z *= s0; h.w *= s0;
    *(float4*)&Xs[lrow * 16 + ((c4 ^ ((lrow >> 1) & 3)) << 2)] = h;
  }
  __syncthreads();
#pragma unroll
  for (int rg = 0; rg < 4; ++rg) {
    int lrow = rg * 256 + rsl;
    int grow = (g << 10) + lrow;
    int deg = degs[rg];
    const unsigned short* nr = nb + ((size_t)lrow << 7);
    float4 acc = make_float4(0.f, 0.f, 0.f, 0.f);
    int dp = deg & ~3, i = 0;
    for (; i < dp; i += 4) {
      unsigned w0 = *(const unsigned*)&nr[i];
      unsigned w1 = *(const unsigned*)&nr[i + 2];
      int jj[4] = {(int)(w0 & 0xffffu), (int)(w0 >> 16),
                   (int)(w1 & 0xffffu), (int)(w1 >> 16)};
      float4 vv[4];
#pragma unroll
      for (int u = 0; u < 4; ++u)
        vv[u] = *(const float4*)&Xs[jj[u] * 16 + ((c4 ^ ((jj[u] >> 1) & 3)) << 2)];
#pragma unroll
      for (int u = 0; u < 4; ++u) {
        acc.x += vv[u].x; acc.y += vv[u].y; acc.z += vv[u].z; acc.w += vv[u].w;
      }
    }
    for (; i < deg; ++i) {
      int j = nr[i];
      float4 v = *(const float4*)&Xs[j * 16 + ((c4 ^ ((j >> 1) & 3)) << 2)];
      acc.x += v.x; acc.y += v.y; acc.z += v.z; acc.w += v.w;
    }
    float d0 = d0g[lrow];
    float4 h = hsave[rg];
    float p = fabsf(h.x - d0 * acc.x) + fabsf(h.y - d0 * acc.y) +
              fabsf(h.z - d0 * acc.z) + fabsf(h.w - d0 * acc.w);
    p += __shfl_xor(p, 1, 64);
    p += __shfl_xor(p, 2, 64);
    if (c4 == 0) partial[(size_t)grow * 8 + cb] = p;
  }
}

__global__ void k_nisred(const float* __restrict__ partial, float* __restrict__ score,
                         int total) {
  int row = blockIdx.x * 256 + threadIdx.x;
  if (row >= total) return;
  float4 a = *(const float4*)&partial[(size_t)row * 8];
  float4 b = *(const float4*)&partial[(size_t)row * 8 + 4];
  score[row] = a.x + a.y + a.z + a.w + b.x + b.y + b.z + b.w;
}

// ---- exact top-k per graph: bitonic sort of (score,idx) packed u64 keys ----
__global__ __launch_bounds__(1024) void k_topk(const float* __restrict__ score,
                                               int* __restrict__ perm, int n, int k) {
  __shared__ unsigned long long keys[1024];
  int b = blockIdx.x, t = threadIdx.x;
  float s = score[b * n + t];
  unsigned ub = __float_as_uint(s);
  unsigned su = (ub & 0x80000000u) ? ~ub : (ub | 0x80000000u);  // monotone map
  keys[t] = ((unsigned long long)(~su) << 32) | (unsigned)t;    // asc sort = desc score, asc idx
  __syncthreads();
  for (int kk = 2; kk <= n; kk <<= 1) {
    for (int j = kk >> 1; j > 0; j >>= 1) {
      int ixj = t ^ j;
      if (ixj > t) {
        unsigned long long a = keys[t], c = keys[ixj];
        bool up = ((t & kk) == 0);
        if ((a > c) == up) { keys[t] = c; keys[ixj] = a; }
      }
      __syncthreads();
    }
  }
  if (t < k) perm[b * k + t] = (int)(keys[t] & 0xffffffffu);
}

// ---- gather pooled rows + attention dots ----
__global__ __launch_bounds__(128) void k_gather(const float* __restrict__ h,
    const int* __restrict__ perm, const float* __restrict__ att, float* __restrict__ Xp,
    float* __restrict__ ar, float* __restrict__ ac, int n, int k) {
  int idx = blockIdx.x, f = threadIdx.x;
  int b = idx / k;
  __shared__ float red[4];
  int p = perm[idx];
  float v = h[((size_t)b * n + p) * Fd + f];
  Xp[(size_t)idx * Fd + f] = v;
  float r1 = wred_sum(v * att[f]);
  float r2 = wred_sum(v * att[Fd + f]);
  if ((f & 63) == 0) { red[f >> 6] = r1; red[2 + (f >> 6)] = r2; }
  __syncthreads();
  if (f == 0) { ar[idx] = red[0] + red[1]; ac[idx] = red[2] + red[3]; }
}

// ---- readout: g[b][0:128] (+)= relu(max), g[b][128:256] (+)= relu(mean) ----
__global__ __launch_bounds__(1024) void k_readout(const float* __restrict__ X, int n,
                                                  float* __restrict__ g, int init) {
  int b = blockIdx.x, t = threadIdx.x;
  int f = t & 127, rs = t >> 7;
  __shared__ float smax[8][128];
  __shared__ float ssum[8][128];
  int per = n >> 3;
  const float* Xs = X + ((size_t)b * n + (size_t)rs * per) * Fd + f;
  float mx = -3.0e38f, sm = 0.f;
  for (int j = 0; j < per; j += 8) {
    float vv[8];
#pragma unroll
    for (int u = 0; u < 8; ++u) vv[u] = Xs[(size_t)(j + u) * Fd];
#pragma unroll
    for (int u = 0; u < 8; ++u) { mx = fmaxf(mx, vv[u]); sm += vv[u]; }
  }
  smax[rs][f] = mx; ssum[rs][f] = sm;
  __syncthreads();
  if (t < 128) {
    float m = smax[0][f], s = ssum[0][f];
#pragma unroll
    for (int q = 1; q < 8; ++q) { m = fmaxf(m, smax[q][f]); s += ssum[q][f]; }
    float a = fmaxf(m, 0.f);
    float m2 = fmaxf(s / (float)n, 0.f);
    if (init) { g[b * 384 + f] = a; g[b * 384 + 128 + f] = m2; }
    else      { g[b * 384 + f] += a; g[b * 384 + 128 + f] += m2; }
  }
}

// ---- A1 = softmax_row(leakyrelu(ar_i+ac_j) + bit(pi,pj)) + row stats ----
__global__ __launch_bounds__(256) void k_buildA_bit(const unsigned* __restrict__ adj,
    const int* __restrict__ perm, const float* __restrict__ ar, const float* __restrict__ ac,
    float* __restrict__ A, float* __restrict__ disc, float* __restrict__ saO,
    float* __restrict__ disn, float* __restrict__ diagO) {
  int wid = threadIdx.x >> 6, lane = threadIdx.x & 63;
  int row = blockIdx.x * 4 + wid;      // [0, Bb*K1)
  int b = row >> 9, i = row & (K1 - 1);
  int pbase = b << 9;
  int pi = perm[pbase + i];
  float ari = ar[pbase + i];
  int j0 = lane * 8;
  float acv[8]; int pj[8];
  *(float4*)&acv[0] = *(const float4*)&ac[pbase + j0];
  *(float4*)&acv[4] = *(const float4*)&ac[pbase + j0 + 4];
  *(int4*)&pj[0] = *(const int4*)&perm[pbase + j0];
  *(int4*)&pj[4] = *(const int4*)&perm[pbase + j0 + 4];
  const unsigned* arow = adj + (size_t)((b << 10) + pi) * 32;
  float xv[8];
#pragma unroll
  for (int u = 0; u < 8; ++u) {
    float x = ari + acv[u];
    x = x > 0.f ? x : 0.2f * x;
    unsigned word = arow[pj[u] >> 5];
    xv[u] = x + (float)((word >> (pj[u] & 31)) & 1u);
  }
  float m = xv[0];
#pragma unroll
  for (int u = 1; u < 8; ++u) m = fmaxf(m, xv[u]);
  m = wred_max_all(m);
  float e[8], ls = 0.f;
#pragma unroll
  for (int u = 0; u < 8; ++u) { e[u] = expf(xv[u] - m); ls += e[u]; }
  float s = wred_sum_all(ls);
  float inv = 1.0f / s;
  float av[8]; float lsum = 0.f;
#pragma unroll
  for (int u = 0; u < 8; ++u) { av[u] = e[u] * inv; lsum += av[u]; }
  float* Ar = A + (size_t)row * K1 + j0;
  *(float4*)&Ar[0] = make_float4(av[0], av[1], av[2], av[3]);
  *(float4*)&Ar[4] = make_float4(av[4], av[5], av[6], av[7]);
  float rs = wred_sum_all(lsum);
  float dsel = av[i & 7];                 // uniform index
  float dval = __shfl(dsel, i >> 3, 64);
  if (lane == 0) {
    float sav = (dval == 0.f) ? 1.f : 0.f;
    float deg = rs + sav;
    disc[row] = deg > 0.f ? rsqrtf(deg) : 0.f;
    saO[row] = sav;
    float deg0 = rs - dval;
    disn[row] = deg0 > 0.f ? rsqrtf(deg0) : 0.f;
    diagO[row] = dval;
  }
}

// ---- A2 = softmax_row(leakyrelu(ar_i+ac_j) + A1[pi,pj]) + row stats ----
__global__ __launch_bounds__(256) void k_buildA_dense(const float* __restrict__ Aprev,
    const int* __restrict__ perm, const float* __restrict__ ar, const float* __restrict__ ac,
    float* __restrict__ A, float* __restrict__ disc, float* __restrict__ saO,
    float* __restrict__ disn, float* __restrict__ diagO) {
  int wid = threadIdx.x >> 6, lane = threadIdx.x & 63;
  int row = blockIdx.x * 4 + wid;      // [0, Bb*K2)
  int b = row >> 8, i = row & (K2 - 1);
  int pbase = b << 8;
  int pi = perm[pbase + i];
  float ari = ar[pbase + i];
  int j0 = lane * 4;
  float acv[4]; int pj[4];
  *(float4*)&acv[0] = *(const float4*)&ac[pbase + j0];
  *(int4*)&pj[0] = *(const int4*)&perm[pbase + j0];
  const float* aprow = Aprev + (size_t)((b << 9) + pi) * K1;
  float xv[4];
#pragma unroll
  for (int u = 0; u < 4; ++u) {
    float x = ari + acv[u];
    x = x > 0.f ? x : 0.2f * x;
    xv[u] = x + aprow[pj[u]];
  }
  float m = fmaxf(fmaxf(xv[0], xv[1]), fmaxf(xv[2], xv[3]));
  m = wred_max_all(m);
  float e[4], ls = 0.f;
#pragma unroll
  for (int u = 0; u < 4; ++u) { e[u] = expf(xv[u] - m); ls += e[u]; }
  float s = wred_sum_all(ls);
  float inv = 1.0f / s;
  float av[4]; float lsum = 0.f;
#pragma unroll
  for (int u = 0; u < 4; ++u) { av[u] = e[u] * inv; lsum += av[u]; }
  *(float4*)&A[(size_t)row * K2 + j0] = make_float4(av[0], av[1], av[2], av[3]);
  float rs = wred_sum_all(lsum);
  float dsel = av[i & 3];
  float dval = __shfl(dsel, i >> 2, 64);
  if (lane == 0) {
    float sav = (dval == 0.f) ? 1.f : 0.f;
    float deg = rs + sav;
    disc[row] = deg > 0.f ? rsqrtf(deg) : 0.f;
    saO[row] = sav;
    float deg0 = rs - dval;
    disn[row] = deg0 > 0.f ? rsqrtf(deg0) : 0.f;
    diagO[row] = dval;
  }
}

// ---- fused dense mm via 3xbf16-split MFMA: out = epilogue(A[b] @ diag(wrow) Y[b]) ----
// BM=64, BN=64 (2 col-tiles in grid), 512 thr = 8 waves; wave w: rows 16*(w&3),
// cols 32*(w>>2) as two 16x16 tiles. K-step 32. a = ah + al (bf16 split);
// D = ah*bh + ah*bl + al*bh accumulated f32 (rel err ~1e-5).
// MODE 0 (conv): h = relu(dc*(acc + sa*dc*Y) + bias)
// MODE 1 (nis):  score[row] += sum_cols |hv - dn*(acc - diag*dn*hv)| (atomic; pre-zeroed)
template <int MODE>
__global__ __launch_bounds__(512) void k_mmf(const float* __restrict__ A,
    const float* __restrict__ Y, const float* __restrict__ wrow,
    const float* __restrict__ aux, const float* __restrict__ bias,
    float* __restrict__ outp, int n) {
  __shared__ unsigned short AsHi[64 * 40], AsLo[64 * 40];
  __shared__ unsigned short YtHi[64 * 40], YtLo[64 * 40];
  int t = threadIdx.x;
  int tiles2 = (n >> 6) << 1;
  int bid = blockIdx.x;
  int c = bid & 7, q = bid >> 3;
  int g = c * 8 + q / tiles2;
  int rem = q % tiles2;
  int rt = rem >> 1, ct = rem & 1;
  const float* Ab = A + (size_t)g * n * n + (size_t)(rt * 64) * n;
  const float* Yb = Y + (size_t)g * n * Fd + ct * 64;
  const float* wb = wrow + (size_t)g * n;
  int sar = t >> 3, sak = (t & 7) << 2;   // A staging: row, k-quad
  int syk = t >> 4, syc = (t & 15) << 2;  // Y staging: k, col-quad
  int w = t >> 6, l = t & 63;
  int tr = w & 3, tcb = (w >> 2) << 1;
  int lr = l & 15, lk = (l >> 4) << 3;
  float4v acc0 = {0.f, 0.f, 0.f, 0.f};
  float4v acc1 = {0.f, 0.f, 0.f, 0.f};
  for (int kb = 0; kb < n; kb += 32) {
    __syncthreads();
    {  // stage A hi/lo
      float4 av = *(const float4*)&Ab[(size_t)sar * n + kb + sak];
      float vs[4] = {av.x, av.y, av.z, av.w};
      unsigned short h[4], lo[4];
#pragma unroll
      for (int i = 0; i < 4; ++i) {
        h[i] = bf16hi(vs[i]);
        float fhi = __uint_as_float(((unsigned)h[i]) << 16);
        lo[i] = bf16hi(vs[i] - fhi);
      }
      uint2 ph, pl;
      ph.x = (unsigned)h[0] | ((unsigned)h[1] << 16);
      ph.y = (unsigned)h[2] | ((unsigned)h[3] << 16);
      pl.x = (unsigned)lo[0] | ((unsigned)lo[1] << 16);
      pl.y = (unsigned)lo[2] | ((unsigned)lo[3] << 16);
      *(uint2*)&AsHi[sar * 40 + sak] = ph;
      *(uint2*)&AsLo[sar * 40 + sak] = pl;
    }
    {  // stage Y transposed hi/lo (scaled by wrow)
      float sc = wb[kb + syk];
      float4 yv = *(const float4*)&Yb[(size_t)(kb + syk) * Fd + syc];
      float vs[4] = {yv.x * sc, yv.y * sc, yv.z * sc, yv.w * sc};
#pragma unroll
      for (int i = 0; i < 4; ++i) {
        unsigned short h = bf16hi(vs[i]);
        float fhi = __uint_as_float(((unsigned)h) << 16);
        unsigned short lo = bf16hi(vs[i] - fhi);
        YtHi[(syc + i) * 40 + syk] = h;
        YtLo[(syc + i) * 40 + syk] = lo;
      }
    }
    __syncthreads();
    short8v ah = *(const short8v*)&AsHi[(16 * tr + lr) * 40 + lk];
    short8v al = *(const short8v*)&AsLo[(16 * tr + lr) * 40 + lk];
    short8v bh0 = *(const short8v*)&YtHi[(16 * tcb + lr) * 40 + lk];
    short8v bl0 = *(const short8v*)&YtLo[(16 * tcb + lr) * 40 + lk];
    short8v bh1 = *(const short8v*)&YtHi[(16 * (tcb + 1) + lr) * 40 + lk];
    short8v bl1 = *(const short8v*)&YtLo[(16 * (tcb + 1) + lr) * 40 + lk];
    acc0 = __builtin_amdgcn_mfma_f32_16x16x32_bf16(ah, bh0, acc0, 0, 0, 0);
    acc0 = __builtin_amdgcn_mfma_f32_16x16x32_bf16(ah, bl0, acc0, 0, 0, 0);
    acc0 = __builtin_amdgcn_mfma_f32_16x16x32_bf16(al, bh0, acc0, 0, 0, 0);
    acc1 = __builtin_amdgcn_mfma_f32_16x16x32_bf16(ah, bh1, acc1, 0, 0, 0);
    acc1 = __builtin_amdgcn_mfma_f32_16x16x32_bf16(ah, bl1, acc1, 0, 0, 0);
    acc1 = __builtin_amdgcn_mfma_f32_16x16x32_bf16(al, bh1, acc1, 0, 0, 0);
  }
  // epilogue: lane l holds D[row=(l>>4)*4+r][col=lr] of each tile
  int colg0 = ct * 64 + 16 * tcb + lr;
  int colg1 = colg0 + 16;
  if (MODE == 0) {
    float bv0 = bias[colg0], bv1 = bias[colg1];
#pragma unroll
    for (int r = 0; r < 4; ++r) {
      int row = rt * 64 + 16 * tr + ((l >> 4) << 2) + r;
      size_t R = (size_t)g * n + row;
      float dc = wb[row];
      float sv = aux[R] * dc;
      float y0 = Y[R * Fd + colg0];
      float y1 = Y[R * Fd + colg1];
      float o0 = fmaxf(dc * (acc0[r] + sv * y0) + bv0, 0.f);
      float o1 = fmaxf(dc * (acc1[r] + sv * y1) + bv1, 0.f);
      outp[R * Fd + colg0] = o0;
      outp[R * Fd + colg1] = o1;
    }
  } else {
#pragma unroll
    for (int r = 0; r < 4; ++r) {
      int row = rt * 64 + 16 * tr + ((l >> 4) << 2) + r;
      size_t R = (size_t)g * n + row;
      float dn = wb[row];
      float dg = aux[R] * dn;
      float h0 = Y[R * Fd + colg0];
      float h1 = Y[R * Fd + colg1];
      float p = fabsf(h0 - dn * (acc0[r] - dg * h0)) +
                fabsf(h1 - dn * (acc1[r] - dg * h1));
      p += __shfl_xor(p, 1, 64);
      p += __shfl_xor(p, 2, 64);
      p += __shfl_xor(p, 4, 64);
      p += __shfl_xor(p, 8, 64);
      if (lr == 0) atomicAdd(&outp[R], p);
    }
  }
}

__global__ __launch_bounds__(128) void k_xskew(const float* __restrict__ skew,
    const float* __restrict__ Wsk, const float* __restrict__ bsk, float* __restrict__ g) {
  int b = blockIdx.x, f = threadIdx.x;
  float acc = bsk[f];
  for (int s = 0; s < 64; ++s) acc += skew[b * 64 + s] * Wsk[s * Fd + f];
  g[b * 384 + 256 + f] = fmaxf(acc, 0.f);
}

__global__ __launch_bounds__(128) void k_mlp1(const float* __restrict__ g,
    const float* __restrict__ Wl, const float* __restrict__ bl, float* __restrict__ o) {
  int b = blockIdx.x, f = threadIdx.x;
  float acc = bl[f];
  for (int s = 0; s < 384; ++s) acc += g[b * 384 + s] * Wl[s * 128 + f];
  o[b * 128 + f] = fmaxf(acc, 0.f);
}
__global__ __launch_bounds__(64) void k_mlp2(const float* __restrict__ x,
    const float* __restrict__ Wl, const float* __restrict__ bl, float* __restrict__ o) {
  int b = blockIdx.x, f = threadIdx.x;
  float acc = bl[f];
  for (int s = 0; s < 128; ++s) acc += x[b * 128 + s] * Wl[s * 64 + f];
  o[b * 64 + f] = fmaxf(acc, 0.f);
}
__global__ __launch_bounds__(64) void k_mlp3(const float* __restrict__ x,
    const float* __restrict__ Wl, const float* __restrict__ bl, float* __restrict__ out) {
  int b = blockIdx.x, f = threadIdx.x;
  __shared__ float lg[10];
  if (f < 10) {
    float acc = bl[f];
    for (int s = 0; s < 64; ++s) acc += x[b * 64 + s] * Wl[s * 10 + f];
    lg[f] = acc;
  }
  __syncthreads();
  if (f == 0) {
    float m = lg[0];
    for (int c = 1; c < 10; ++c) m = fmaxf(m, lg[c]);
    float s = 0.f;
    for (int c = 0; c < 10; ++c) s += expf(lg[c] - m);
    float l = logf(s);
    for (int c = 0; c < 10; ++c) out[b * 10 + c] = lg[c] - m - l;
  }
}

extern "C" void kernel_launch(void* const* d_in, const int* in_sizes, int n_in,
                              void* d_out, int out_size, void* d_ws, size_t ws_size,
                              hipStream_t stream) {
  const float* x    = (const float*)d_in[0];
  const int*   src  = (const int*)d_in[1];
  const int*   dst  = (const int*)d_in[2];
  const float* skew = (const float*)d_in[3];
  const float* W1   = (const float*)d_in[4];
  const float* b1   = (const float*)d_in[5];
  const float* W2   = (const float*)d_in[6];
  const float* b2   = (const float*)d_in[7];
  const float* W3   = (const float*)d_in[8];
  const float* b3   = (const float*)d_in[9];
  const float* att1 = (const float*)d_in[10];
  const float* att2 = (const float*)d_in[11];
  const float* Wsk  = (const float*)d_in[12];
  const float* bsk  = (const float*)d_in[13];
  const float* Wl1  = (const float*)d_in[14];
  const float* bl1  = (const float*)d_in[15];
  const float* Wl2  = (const float*)d_in[16];
  const float* bl2  = (const float*)d_in[17];
  const float* Wl3  = (const float*)d_in[18];
  const float* bl3  = (const float*)d_in[19];
  float* out = (float*)d_out;

  char* base = (char*)d_ws;
  size_t off = 0;
  auto alloc = [&](size_t bytes) -> void* {
    void* p = base + off;
    off += (bytes + 255) & ~(size_t)255;
    return p;
  };

  unsigned* adj = (unsigned*)alloc((size_t)Bb * N0 * 32 * 4);        // 8 MB
  float* dis0 = (float*)alloc((size_t)Bb * N0 * 4);
  float* dis1 = (float*)alloc((size_t)Bb * N0 * 4);
  int*   degv = (int*)alloc((size_t)Bb * N0 * 4);
  float* bigA = (float*)alloc((size_t)64 * 1024 * 1024);             // 64 MB multi-use
  float* XW  = bigA;                                                  // [B,1024,128]
  float* h1  = bigA + (size_t)Bb * N0 * Fd;                           // [B,1024,128]
  float* A1  = bigA;                                                  // [B,512,512] (after h1 dead)
  float* XW3 = bigA;                                                  // [B,256,128] (after A1 dead)
  float* h3  = bigA + (size_t)Bb * K2 * Fd;                           // [B,256,128]
  float* score = (float*)alloc((size_t)Bb * N0 * 4);
  float* partial = (float*)alloc((size_t)Bb * N0 * 8 * 4);            // 2 MB
  int*   perm1 = (int*)alloc((size_t)Bb * K1 * 4);
  float* Xp1 = (float*)alloc((size_t)Bb * K1 * Fd * 4);               // later reused as A2
  float* A2  = Xp1;                                                   // [B,256,256] = same bytes
  float* ar1 = (float*)alloc((size_t)Bb * K1 * 4);
  float* ac1 = (float*)alloc((size_t)Bb * K1 * 4);
  float* disc2 = (float*)alloc((size_t)Bb * K1 * 4);
  float* sa2   = (float*)alloc((size_t)Bb * K1 * 4);
  float* disn2 = (float*)alloc((size_t)Bb * K1 * 4);
  float* diag2 = (float*)alloc((size_t)Bb * K1 * 4);
  float* XW2 = (float*)alloc((size_t)Bb * K1 * Fd * 4);               // 16 MB
  float* h2  = (float*)alloc((size_t)Bb * K1 * Fd * 4);               // 16 MB
  int*   perm2 = (int*)alloc((size_t)Bb * K2 * 4);
  float* Xp2 = (float*)alloc((size_t)Bb * K2 * Fd * 4);
  float* ar2 = (float*)alloc((size_t)Bb * K2 * 4);
  float* ac2 = (float*)alloc((size_t)Bb * K2 * 4);
  float* disc3 = (float*)alloc((size_t)Bb * K2 * 4);
  float* sa3   = (float*)alloc((size_t)Bb * K2 * 4);
  float* disn3 = (float*)alloc((size_t)Bb * K2 * 4);
  float* diag3 = (float*)alloc((size_t)Bb * K2 * 4);
  float* g  = (float*)alloc((size_t)Bb * 384 * 4);
  float* t1 = (float*)alloc((size_t)Bb * 128 * 4);
  float* t2 = (float*)alloc((size_t)Bb * 64 * 4);
  // nbr [B*N0][128] u16 = 16 MB; overlays XW2 (dead until stage-2 gemm)
  unsigned short* nbr = (unsigned short*)XW2;
  (void)ws_size; (void)in_sizes; (void)n_in; (void)out_size;

  // stage 1: fused graph build, gemm, fused conv+nis (LDS-staged, float4 gathers)
  k_graph<<<Bb * 4, 1024, 0, stream>>>(src, dst, adj, nbr, degv, dis0, dis1);
  k_gemm128<<<Bb * N0 / 64, 256, 0, stream>>>(x, W1, XW);
  k_convnis<<<Bb * 8, 1024, 0, stream>>>(nbr, degv, XW, dis0, dis1, b1, h1, partial);
  k_nisred<<<(Bb * N0 + 255) / 256, 256, 0, stream>>>(partial, score, Bb * N0);
  k_topk<<<Bb, N0, 0, stream>>>(score, perm1, N0, K1);
  k_gather<<<Bb * K1, 128, 0, stream>>>(h1, perm1, att1, Xp1, ar1, ac1, N0, K1);
  k_readout<<<Bb, 1024, 0, stream>>>(Xp1, K1, g, 1);
  k_buildA_bit<<<Bb * K1 / 4, 256, 0, stream>>>(adj, perm1, ar1, ac1, A1,
                                                disc2, sa2, disn2, diag2);  // overwrites XW/h1

  // stage 2: dense A1 (MFMA 3xbf16-split mm + fused epilogues)
  k_gemm128<<<Bb * K1 / 64, 256, 0, stream>>>(Xp1, W2, XW2);
  k_mmf<0><<<Bb * (K1 / 64) * 2, 512, 0, stream>>>(A1, XW2, disc2, sa2, b2, h2, K1);
  hipMemsetAsync(score, 0, (size_t)Bb * K1 * 4, stream);
  k_mmf<1><<<Bb * (K1 / 64) * 2, 512, 0, stream>>>(A1, h2, disn2, diag2, nullptr, score, K1);
  k_topk<<<Bb, K1, 0, stream>>>(score, perm2, K1, K2);
  k_gather<<<Bb * K2, 128, 0, stream>>>(h2, perm2, att2, Xp2, ar2, ac2, K1, K2);
  k_readout<<<Bb, 1024, 0, stream>>>(Xp2, K2, g, 0);
  k_buildA_dense<<<Bb * K2 / 4, 256, 0, stream>>>(A1, perm2, ar2, ac2, A2,
                                                  disc3, sa3, disn3, diag3);  // overwrites Xp1

  // stage 3: dense A2
  k_gemm128<<<Bb * K2 / 64, 256, 0, stream>>>(Xp2, W3, XW3);           // overwrites A1 region
  k_mmf<0><<<Bb * (K2 / 64) * 2, 512, 0, stream>>>(A2, XW3, disc3, sa3, b3, h3, K2);
  k_readout<<<Bb, 1024, 0, stream>>>(h3, K2, g, 0);

  // head
  k_xskew<<<Bb, 128, 0, stream>>>(skew, Wsk, bsk, g);
  k_mlp1<<<Bb, 128, 0, stream>>>(g, Wl1, bl1, t1);
  k_mlp2<<<Bb, 64, 0, stream>>>(t1, Wl2, bl2, t2);
  k_mlp3<<<Bb, 64, 0, stream>>>(t2, Wl3, bl3, out);
}

// Round 12
// 374.501 us; speedup vs baseline: 1.2521x; 1.0475x over previous
//
#include <hip/hip_runtime.h>
#include <math.h>

#define Bb 64
#define N0 1024
#define NE 16384
#define Fd 128
#define K1 512
#define K2 256
#define RPB 256  // rows per k_graph block

typedef __attribute__((ext_vector_type(8))) short short8v;
typedef __attribute__((ext_vector_type(4))) float float4v;

__device__ __forceinline__ float wred_sum(float v) {
#pragma unroll
  for (int o = 32; o > 0; o >>= 1) v += __shfl_down(v, o, 64);
  return v;
}
__device__ __forceinline__ float wred_sum_all(float v) {
#pragma unroll
  for (int o = 32; o > 0; o >>= 1) v += __shfl_xor(v, o, 64);
  return v;
}
__device__ __forceinline__ float wred_max_all(float v) {
#pragma unroll
  for (int o = 32; o > 0; o >>= 1) v = fmaxf(v, __shfl_xor(v, o, 64));
  return v;
}
__device__ __forceinline__ unsigned short bf16hi(float x) {
  unsigned u = __float_as_uint(x);
  return (unsigned short)((u + 0x7fffu + ((u >> 16) & 1u)) >> 16);
}

// ---- fused graph build: edges -> LDS bitmask -> adj + degree + nbr list ----
// nbr entries are PRE-SWIZZLED: s = (j<<2)|(j&3); consumer addr = (s^c4)<<4 bytes.
__global__ __launch_bounds__(1024) void k_graph(const int* __restrict__ src,
    const int* __restrict__ dst, unsigned* __restrict__ adj,
    unsigned short* __restrict__ nbr, int* __restrict__ degv,
    float* __restrict__ dis0, float* __restrict__ dis1) {
  __shared__ unsigned lmask[RPB * 32];  // 32 KB
  int t = threadIdx.x;
  int b = blockIdx.x >> 2;
  int rlo = (blockIdx.x & 3) * RPB;
#pragma unroll
  for (int i = t; i < RPB * 32; i += 1024) lmask[i] = 0;
  __syncthreads();
  const int* sp = src + b * NE;
  const int* dp = dst + b * NE;
#pragma unroll
  for (int e = t; e < NE; e += 1024) {
    int u = sp[e], v = dp[e];
    if (u == v) continue;
    if ((unsigned)(u - rlo) < RPB)
      atomicOr(&lmask[(u - rlo) * 32 + (v >> 5)], 1u << (v & 31));
    if ((unsigned)(v - rlo) < RPB)
      atomicOr(&lmask[(v - rlo) * 32 + (u >> 5)], 1u << (u & 31));
  }
  __syncthreads();
  unsigned* adjg = adj + ((size_t)(b << 10) + rlo) * 32;
#pragma unroll
  for (int i = t; i < RPB * 32; i += 1024) adjg[i] = lmask[i];
  if (t < RPB) {
    int row = (b << 10) + rlo + t;
    const unsigned* wm = &lmask[t * 32];
    int d = 0;
#pragma unroll
    for (int i = 0; i < 32; ++i) d += __popc(wm[i]);
    degv[row] = d;
    dis0[row] = d > 0 ? rsqrtf((float)d) : 0.f;
    dis1[row] = rsqrtf((float)(d + 1));
    unsigned short* dstp = nbr + (size_t)row * 128;
    int o = 0;
#pragma unroll
    for (int w = 0; w < 32; ++w) {
      unsigned m = wm[w];
      int bas = w << 5;
      while (m) {
        int j = bas + __ffs(m) - 1; m &= m - 1;
        dstp[o++] = (unsigned short)((j << 2) | (j & 3));
      }
    }
  }
}

// ---- C[M,128] = X[M,128] @ W[128,128], M % 64 == 0, grid = M/64, block 256 ----
__global__ __launch_bounds__(256) void k_gemm128(const float* __restrict__ X,
                                                 const float* __restrict__ W,
                                                 float* __restrict__ C) {
  __shared__ float Xs[64][132];
  __shared__ float Ws[32][132];
  int t = threadIdx.x;
  size_t row0 = (size_t)blockIdx.x * 64;
  const float4* Xg = (const float4*)(X + row0 * Fd);
#pragma unroll
  for (int i = 0; i < 8; ++i) {
    int f4 = t + 256 * i;
    float4 v = Xg[f4];
    *(float4*)&Xs[f4 >> 5][(f4 & 31) * 4] = v;
  }
  int r0 = (t >> 5) * 8, c0 = (t & 31) * 4;
  float acc[8][4] = {};
  for (int kb = 0; kb < 128; kb += 32) {
    __syncthreads();
#pragma unroll
    for (int i = 0; i < 4; ++i) {
      int f4 = t + 256 * i;
      float4 v = ((const float4*)(W + (size_t)kb * Fd))[f4];
      *(float4*)&Ws[f4 >> 5][(f4 & 31) * 4] = v;
    }
    __syncthreads();
#pragma unroll
    for (int k = 0; k < 32; ++k) {
      float4 wv = *(const float4*)&Ws[k][c0];
#pragma unroll
      for (int i = 0; i < 8; ++i) {
        float xv = Xs[r0 + i][kb + k];
        acc[i][0] += xv * wv.x; acc[i][1] += xv * wv.y;
        acc[i][2] += xv * wv.z; acc[i][3] += xv * wv.w;
      }
    }
  }
#pragma unroll
  for (int i = 0; i < 8; ++i) {
    float4 o = make_float4(acc[i][0], acc[i][1], acc[i][2], acc[i][3]);
    *(float4*)&C[(row0 + r0 + i) * Fd + c0] = o;
  }
}

// ---- fused conv1 + NIS via LDS-staged source, pre-swizzled offsets ----
// block = (graph, 16-col slice); c4 = t&3 (logical col quad), rsl = t>>2.
// LDS layout: row r physical slot sl holds logical quad sl^(r&3).
__global__ __launch_bounds__(1024) void k_convnis(const unsigned short* __restrict__ nbr,
    const int* __restrict__ degv, const float* __restrict__ XW,
    const float* __restrict__ dis0, const float* __restrict__ dis1,
    const float* __restrict__ b1, float* __restrict__ h1, float* __restrict__ partial) {
  __shared__ float Xs[N0 * 16];  // 64 KB
  int t = threadIdx.x;
  int g = blockIdx.x & 63;
  int cb = blockIdx.x >> 6;
  int c16 = cb * 16;
  const float* XWg = XW + ((size_t)(g << 10)) * Fd + c16;
  const float* d1g = dis1 + (g << 10);
  const float* d0g = dis0 + (g << 10);
  {
    int r = t;
    float s = d1g[r];
    int sw = r & 3;
#pragma unroll
    for (int sl = 0; sl < 4; ++sl) {
      int lc = sl ^ sw;
      float4 v = *(const float4*)&XWg[(size_t)r * Fd + lc * 4];
      v.x *= s; v.y *= s; v.z *= s; v.w *= s;
      *(float4*)&Xs[r * 16 + sl * 4] = v;
    }
  }
  __syncthreads();
  int c4 = t & 3, rsl = t >> 2;
  const unsigned short* nb = nbr + (((size_t)(g << 10)) << 7);
  float4 bv = *(const float4*)&b1[c16 + c4 * 4];
  float4 hsave[4];
  int degs[4];
  const char* Xb = (const char*)Xs;
  int cx = c4 << 4;  // XOR constant in byte space
#pragma unroll
  for (int rg = 0; rg < 4; ++rg) {
    int lrow = rg * 256 + rsl;
    int grow = (g << 10) + lrow;
    int deg = degv[grow];
    degs[rg] = deg;
    const unsigned short* nr = nb + ((size_t)lrow << 7);
    float4 acc = make_float4(0.f, 0.f, 0.f, 0.f);
    int dp = deg & ~7, i = 0;
    for (; i < dp; i += 8) {
      uint4 w = *(const uint4*)&nr[i];
      int s_[8] = {(int)(w.x & 0xffffu), (int)(w.x >> 16),
                   (int)(w.y & 0xffffu), (int)(w.y >> 16),
                   (int)(w.z & 0xffffu), (int)(w.z >> 16),
                   (int)(w.w & 0xffffu), (int)(w.w >> 16)};
      float4 vv[8];
#pragma unroll
      for (int u = 0; u < 8; ++u)
        vv[u] = *(const float4*)(Xb + ((s_[u] << 4) ^ cx));
#pragma unroll
      for (int u = 0; u < 8; ++u) {
        acc.x += vv[u].x; acc.y += vv[u].y; acc.z += vv[u].z; acc.w += vv[u].w;
      }
    }
    for (; i < deg; ++i) {
      int s = nr[i];
      float4 v = *(const float4*)(Xb + ((s << 4) ^ cx));
      acc.x += v.x; acc.y += v.y; acc.z += v.z; acc.w += v.w;
    }
    float di = d1g[lrow];
    int sself = (lrow << 2) | (lrow & 3);
    float4 self = *(const float4*)(Xb + ((sself << 4) ^ cx));
    float4 h;
    h.x = fmaxf(di * (acc.x + self.x) + bv.x, 0.f);
    h.y = fmaxf(di * (acc.y + self.y) + bv.y, 0.f);
    h.z = fmaxf(di * (acc.z + self.z) + bv.z, 0.f);
    h.w = fmaxf(di * (acc.w + self.w) + bv.w, 0.f);
    hsave[rg] = h;
    *(float4*)&h1[(size_t)grow * Fd + c16 + c4 * 4] = h;
  }
  __syncthreads();
#pragma unroll
  for (int rg = 0; rg < 4; ++rg) {
    int lrow = rg * 256 + rsl;
    float s0 = d0g[lrow];
    float4 h = hsave[rg];
    h.x *= s0; h.y *= s0; h.z *= s0; h.w *= s0;
    int sself = (lrow << 2) | (lrow & 3);
    *(float4*)((char*)Xs + ((sself << 4) ^ cx)) = h;
  }
  __syncthreads();
#pragma unroll
  for (int rg = 0; rg < 4; ++rg) {
    int lrow = rg * 256 + rsl;
    int grow = (g << 10) + lrow;
    int deg = degs[rg];
    const unsigned short* nr = nb + ((size_t)lrow << 7);
    float4 acc = make_float4(0.f, 0.f, 0.f, 0.f);
    int dp = deg & ~7, i = 0;
    for (; i < dp; i += 8) {
      uint4 w = *(const uint4*)&nr[i];
      int s_[8] = {(int)(w.x & 0xffffu), (int)(w.x >> 16),
                   (int)(w.y & 0xffffu), (int)(w.y >> 16),
                   (int)(w.z & 0xffffu), (int)(w.z >> 16),
                   (int)(w.w & 0xffffu), (int)(w.w >> 16)};
      float4 vv[8];
#pragma unroll
      for (int u = 0; u < 8; ++u)
        vv[u] = *(const float4*)(Xb + ((s_[u] << 4) ^ cx));
#pragma unroll
      for (int u = 0; u < 8; ++u) {
        acc.x += vv[u].x; acc.y += vv[u].y; acc.z += vv[u].z; acc.w += vv[u].w;
      }
    }
    for (; i < deg; ++i) {
      int s = nr[i];
      float4 v = *(const float4*)(Xb + ((s << 4) ^ cx));
      acc.x += v.x; acc.y += v.y; acc.z += v.z; acc.w += v.w;
    }
    float d0 = d0g[lrow];
    float4 h = hsave[rg];
    float p = fabsf(h.x - d0 * acc.x) + fabsf(h.y - d0 * acc.y) +
              fabsf(h.z - d0 * acc.z) + fabsf(h.w - d0 * acc.w);
    p += __shfl_xor(p, 1, 64);
    p += __shfl_xor(p, 2, 64);
    if (c4 == 0) partial[(size_t)grow * 8 + cb] = p;
  }
}

// ---- exact top-k per graph; loads sum of ps partials per row ----
__global__ __launch_bounds__(1024) void k_topk(const float* __restrict__ score,
                                               int* __restrict__ perm, int n, int k,
                                               int ps) {
  __shared__ unsigned long long keys[1024];
  int b = blockIdx.x, t = threadIdx.x;
  float s = 0.f;
  const float* p = score + ((size_t)b * n + t) * ps;
  for (int i = 0; i < ps; ++i) s += p[i];
  unsigned ub = __float_as_uint(s);
  unsigned su = (ub & 0x80000000u) ? ~ub : (ub | 0x80000000u);  // monotone map
  keys[t] = ((unsigned long long)(~su) << 32) | (unsigned)t;    // asc sort = desc score, asc idx
  __syncthreads();
  for (int kk = 2; kk <= n; kk <<= 1) {
    for (int j = kk >> 1; j > 0; j >>= 1) {
      int ixj = t ^ j;
      if (ixj > t) {
        unsigned long long a = keys[t], c = keys[ixj];
        bool up = ((t & kk) == 0);
        if ((a > c) == up) { keys[t] = c; keys[ixj] = a; }
      }
      __syncthreads();
    }
  }
  if (t < k) perm[b * k + t] = (int)(keys[t] & 0xffffffffu);
}

// ---- gather pooled rows + attention dots ----
__global__ __launch_bounds__(128) void k_gather(const float* __restrict__ h,
    const int* __restrict__ perm, const float* __restrict__ att, float* __restrict__ Xp,
    float* __restrict__ ar, float* __restrict__ ac, int n, int k) {
  int idx = blockIdx.x, f = threadIdx.x;
  int b = idx / k;
  __shared__ float red[4];
  int p = perm[idx];
  float v = h[((size_t)b * n + p) * Fd + f];
  Xp[(size_t)idx * Fd + f] = v;
  float r1 = wred_sum(v * att[f]);
  float r2 = wred_sum(v * att[Fd + f]);
  if ((f & 63) == 0) { red[f >> 6] = r1; red[2 + (f >> 6)] = r2; }
  __syncthreads();
  if (f == 0) { ar[idx] = red[0] + red[1]; ac[idx] = red[2] + red[3]; }
}

// ---- readout: g[b][0:128] (+)= relu(max), g[b][128:256] (+)= relu(mean) ----
__global__ __launch_bounds__(1024) void k_readout(const float* __restrict__ X, int n,
                                                  float* __restrict__ g, int init) {
  int b = blockIdx.x, t = threadIdx.x;
  int f = t & 127, rs = t >> 7;
  __shared__ float smax[8][128];
  __shared__ float ssum[8][128];
  int per = n >> 3;
  const float* Xs = X + ((size_t)b * n + (size_t)rs * per) * Fd + f;
  float mx = -3.0e38f, sm = 0.f;
  for (int j = 0; j < per; j += 8) {
    float vv[8];
#pragma unroll
    for (int u = 0; u < 8; ++u) vv[u] = Xs[(size_t)(j + u) * Fd];
#pragma unroll
    for (int u = 0; u < 8; ++u) { mx = fmaxf(mx, vv[u]); sm += vv[u]; }
  }
  smax[rs][f] = mx; ssum[rs][f] = sm;
  __syncthreads();
  if (t < 128) {
    float m = smax[0][f], s = ssum[0][f];
#pragma unroll
    for (int q = 1; q < 8; ++q) { m = fmaxf(m, smax[q][f]); s += ssum[q][f]; }
    float a = fmaxf(m, 0.f);
    float m2 = fmaxf(s / (float)n, 0.f);
    if (init) { g[b * 384 + f] = a; g[b * 384 + 128 + f] = m2; }
    else      { g[b * 384 + f] += a; g[b * 384 + 128 + f] += m2; }
  }
}

// ---- A1 = softmax_row(leakyrelu(ar_i+ac_j) + bit(pi,pj)) + row stats ----
__global__ __launch_bounds__(256) void k_buildA_bit(const unsigned* __restrict__ adj,
    const int* __restrict__ perm, const float* __restrict__ ar, const float* __restrict__ ac,
    float* __restrict__ A, float* __restrict__ disc, float* __restrict__ saO,
    float* __restrict__ disn, float* __restrict__ diagO) {
  int wid = threadIdx.x >> 6, lane = threadIdx.x & 63;
  int row = blockIdx.x * 4 + wid;      // [0, Bb*K1)
  int b = row >> 9, i = row & (K1 - 1);
  int pbase = b << 9;
  int pi = perm[pbase + i];
  float ari = ar[pbase + i];
  int j0 = lane * 8;
  float acv[8]; int pj[8];
  *(float4*)&acv[0] = *(const float4*)&ac[pbase + j0];
  *(float4*)&acv[4] = *(const float4*)&ac[pbase + j0 + 4];
  *(int4*)&pj[0] = *(const int4*)&perm[pbase + j0];
  *(int4*)&pj[4] = *(const int4*)&perm[pbase + j0 + 4];
  const unsigned* arow = adj + (size_t)((b << 10) + pi) * 32;
  float xv[8];
#pragma unroll
  for (int u = 0; u < 8; ++u) {
    float x = ari + acv[u];
    x = x > 0.f ? x : 0.2f * x;
    unsigned word = arow[pj[u] >> 5];
    xv[u] = x + (float)((word >> (pj[u] & 31)) & 1u);
  }
  float m = xv[0];
#pragma unroll
  for (int u = 1; u < 8; ++u) m = fmaxf(m, xv[u]);
  m = wred_max_all(m);
  float e[8], ls = 0.f;
#pragma unroll
  for (int u = 0; u < 8; ++u) { e[u] = expf(xv[u] - m); ls += e[u]; }
  float s = wred_sum_all(ls);
  float inv = 1.0f / s;
  float av[8]; float lsum = 0.f;
#pragma unroll
  for (int u = 0; u < 8; ++u) { av[u] = e[u] * inv; lsum += av[u]; }
  float* Ar = A + (size_t)row * K1 + j0;
  *(float4*)&Ar[0] = make_float4(av[0], av[1], av[2], av[3]);
  *(float4*)&Ar[4] = make_float4(av[4], av[5], av[6], av[7]);
  float rs = wred_sum_all(lsum);
  float dsel = av[i & 7];                 // uniform index
  float dval = __shfl(dsel, i >> 3, 64);
  if (lane == 0) {
    float sav = (dval == 0.f) ? 1.f : 0.f;
    float deg = rs + sav;
    disc[row] = deg > 0.f ? rsqrtf(deg) : 0.f;
    saO[row] = sav;
    float deg0 = rs - dval;
    disn[row] = deg0 > 0.f ? rsqrtf(deg0) : 0.f;
    diagO[row] = dval;
  }
}

// ---- A2 = softmax_row(leakyrelu(ar_i+ac_j) + A1[pi,pj]) + row stats ----
__global__ __launch_bounds__(256) void k_buildA_dense(const float* __restrict__ Aprev,
    const int* __restrict__ perm, const float* __restrict__ ar, const float* __restrict__ ac,
    float* __restrict__ A, float* __restrict__ disc, float* __restrict__ saO,
    float* __restrict__ disn, float* __restrict__ diagO) {
  int wid = threadIdx.x >> 6, lane = threadIdx.x & 63;
  int row = blockIdx.x * 4 + wid;      // [0, Bb*K2)
  int b = row >> 8, i = row & (K2 - 1);
  int pbase = b << 8;
  int pi = perm[pbase + i];
  float ari = ar[pbase + i];
  int j0 = lane * 4;
  float acv[4]; int pj[4];
  *(float4*)&acv[0] = *(const float4*)&ac[pbase + j0];
  *(int4*)&pj[0] = *(const int4*)&perm[pbase + j0];
  const float* aprow = Aprev + (size_t)((b << 9) + pi) * K1;
  float xv[4];
#pragma unroll
  for (int u = 0; u < 4; ++u) {
    float x = ari + acv[u];
    x = x > 0.f ? x : 0.2f * x;
    xv[u] = x + aprow[pj[u]];
  }
  float m = fmaxf(fmaxf(xv[0], xv[1]), fmaxf(xv[2], xv[3]));
  m = wred_max_all(m);
  float e[4], ls = 0.f;
#pragma unroll
  for (int u = 0; u < 4; ++u) { e[u] = expf(xv[u] - m); ls += e[u]; }
  float s = wred_sum_all(ls);
  float inv = 1.0f / s;
  float av[4]; float lsum = 0.f;
#pragma unroll
  for (int u = 0; u < 4; ++u) { av[u] = e[u] * inv; lsum += av[u]; }
  *(float4*)&A[(size_t)row * K2 + j0] = make_float4(av[0], av[1], av[2], av[3]);
  float rs = wred_sum_all(lsum);
  float dsel = av[i & 3];
  float dval = __shfl(dsel, i >> 2, 64);
  if (lane == 0) {
    float sav = (dval == 0.f) ? 1.f : 0.f;
    float deg = rs + sav;
    disc[row] = deg > 0.f ? rsqrtf(deg) : 0.f;
    saO[row] = sav;
    float deg0 = rs - dval;
    disn[row] = deg0 > 0.f ? rsqrtf(deg0) : 0.f;
    diagO[row] = dval;
  }
}

// ---- fused dense mm via 3xbf16-split MFMA ----
// MODE 0 (conv): h = relu(dc*(acc + sa*dc*Y) + bias)
// MODE 1 (nis):  score2[row*2+ct] = col-tile partial of sum |hv - dn*(acc - diag*dn*hv)|
template <int MODE>
__global__ __launch_bounds__(512) void k_mmf(const float* __restrict__ A,
    const float* __restrict__ Y, const float* __restrict__ wrow,
    const float* __restrict__ aux, const float* __restrict__ bias,
    float* __restrict__ outp, int n) {
  __shared__ unsigned short AsHi[64 * 40], AsLo[64 * 40];
  __shared__ unsigned short YtHi[64 * 40], YtLo[64 * 40];
  int t = threadIdx.x;
  int tiles2 = (n >> 6) << 1;
  int bid = blockIdx.x;
  int c = bid & 7, q = bid >> 3;
  int g = c * 8 + q / tiles2;
  int rem = q % tiles2;
  int rt = rem >> 1, ct = rem & 1;
  const float* Ab = A + (size_t)g * n * n + (size_t)(rt * 64) * n;
  const float* Yb = Y + (size_t)g * n * Fd + ct * 64;
  const float* wb = wrow + (size_t)g * n;
  int sar = t >> 3, sak = (t & 7) << 2;   // A staging: row, k-quad
  int syk = t >> 4, syc = (t & 15) << 2;  // Y staging: k, col-quad
  int w = t >> 6, l = t & 63;
  int tr = w & 3, tcb = (w >> 2) << 1;
  int lr = l & 15, lk = (l >> 4) << 3;
  float4v acc0 = {0.f, 0.f, 0.f, 0.f};
  float4v acc1 = {0.f, 0.f, 0.f, 0.f};
  for (int kb = 0; kb < n; kb += 32) {
    __syncthreads();
    {  // stage A hi/lo
      float4 av = *(const float4*)&Ab[(size_t)sar * n + kb + sak];
      float vs[4] = {av.x, av.y, av.z, av.w};
      unsigned short h[4], lo[4];
#pragma unroll
      for (int i = 0; i < 4; ++i) {
        h[i] = bf16hi(vs[i]);
        float fhi = __uint_as_float(((unsigned)h[i]) << 16);
        lo[i] = bf16hi(vs[i] - fhi);
      }
      uint2 ph, pl;
      ph.x = (unsigned)h[0] | ((unsigned)h[1] << 16);
      ph.y = (unsigned)h[2] | ((unsigned)h[3] << 16);
      pl.x = (unsigned)lo[0] | ((unsigned)lo[1] << 16);
      pl.y = (unsigned)lo[2] | ((unsigned)lo[3] << 16);
      *(uint2*)&AsHi[sar * 40 + sak] = ph;
      *(uint2*)&AsLo[sar * 40 + sak] = pl;
    }
    {  // stage Y transposed hi/lo (scaled by wrow)
      float sc = wb[kb + syk];
      float4 yv = *(const float4*)&Yb[(size_t)(kb + syk) * Fd + syc];
      float vs[4] = {yv.x * sc, yv.y * sc, yv.z * sc, yv.w * sc};
#pragma unroll
      for (int i = 0; i < 4; ++i) {
        unsigned short h = bf16hi(vs[i]);
        float fhi = __uint_as_float(((unsigned)h) << 16);
        unsigned short lo = bf16hi(vs[i] - fhi);
        YtHi[(syc + i) * 40 + syk] = h;
        YtLo[(syc + i) * 40 + syk] = lo;
      }
    }
    __syncthreads();
    short8v ah = *(const short8v*)&AsHi[(16 * tr + lr) * 40 + lk];
    short8v al = *(const short8v*)&AsLo[(16 * tr + lr) * 40 + lk];
    short8v bh0 = *(const short8v*)&YtHi[(16 * tcb + lr) * 40 + lk];
    short8v bl0 = *(const short8v*)&YtLo[(16 * tcb + lr) * 40 + lk];
    short8v bh1 = *(const short8v*)&YtHi[(16 * (tcb + 1) + lr) * 40 + lk];
    short8v bl1 = *(const short8v*)&YtLo[(16 * (tcb + 1) + lr) * 40 + lk];
    acc0 = __builtin_amdgcn_mfma_f32_16x16x32_bf16(ah, bh0, acc0, 0, 0, 0);
    acc0 = __builtin_amdgcn_mfma_f32_16x16x32_bf16(ah, bl0, acc0, 0, 0, 0);
    acc0 = __builtin_amdgcn_mfma_f32_16x16x32_bf16(al, bh0, acc0, 0, 0, 0);
    acc1 = __builtin_amdgcn_mfma_f32_16x16x32_bf16(ah, bh1, acc1, 0, 0, 0);
    acc1 = __builtin_amdgcn_mfma_f32_16x16x32_bf16(ah, bl1, acc1, 0, 0, 0);
    acc1 = __builtin_amdgcn_mfma_f32_16x16x32_bf16(al, bh1, acc1, 0, 0, 0);
  }
  // epilogue: lane l holds D[row=(l>>4)*4+r][col=lr] of each tile
  int colg0 = ct * 64 + 16 * tcb + lr;
  int colg1 = colg0 + 16;
  if (MODE == 0) {
    float bv0 = bias[colg0], bv1 = bias[colg1];
#pragma unroll
    for (int r = 0; r < 4; ++r) {
      int row = rt * 64 + 16 * tr + ((l >> 4) << 2) + r;
      size_t R = (size_t)g * n + row;
      float dc = wb[row];
      float sv = aux[R] * dc;
      float y0 = Y[R * Fd + colg0];
      float y1 = Y[R * Fd + colg1];
      float o0 = fmaxf(dc * (acc0[r] + sv * y0) + bv0, 0.f);
      float o1 = fmaxf(dc * (acc1[r] + sv * y1) + bv1, 0.f);
      outp[R * Fd + colg0] = o0;
      outp[R * Fd + colg1] = o1;
    }
  } else {
#pragma unroll
    for (int r = 0; r < 4; ++r) {
      int row = rt * 64 + 16 * tr + ((l >> 4) << 2) + r;
      size_t R = (size_t)g * n + row;
      float dn = wb[row];
      float dg = aux[R] * dn;
      float h0 = Y[R * Fd + colg0];
      float h1 = Y[R * Fd + colg1];
      float p = fabsf(h0 - dn * (acc0[r] - dg * h0)) +
                fabsf(h1 - dn * (acc1[r] - dg * h1));
      p += __shfl_xor(p, 1, 64);
      p += __shfl_xor(p, 2, 64);
      p += __shfl_xor(p, 4, 64);
      p += __shfl_xor(p, 8, 64);
      if (lr == 0) outp[R * 2 + ct] = p;
    }
  }
}

// ---- fused head: xskew + mlp1 + mlp2 + mlp3 + log_softmax ----
__global__ __launch_bounds__(128) void k_head(const float* __restrict__ gin,
    const float* __restrict__ skew, const float* __restrict__ Wsk,
    const float* __restrict__ bsk, const float* __restrict__ Wl1,
    const float* __restrict__ bl1, const float* __restrict__ Wl2,
    const float* __restrict__ bl2, const float* __restrict__ Wl3,
    const float* __restrict__ bl3, float* __restrict__ out) {
  __shared__ float gl[384];
  __shared__ float t1s[128];
  __shared__ float t2s[64];
  __shared__ float lg[10];
  int b = blockIdx.x, f = threadIdx.x;
  gl[f] = gin[b * 384 + f];
  gl[128 + f] = gin[b * 384 + 128 + f];
  float acc = bsk[f];
  for (int s = 0; s < 64; ++s) acc += skew[b * 64 + s] * Wsk[s * Fd + f];
  gl[256 + f] = fmaxf(acc, 0.f);
  __syncthreads();
  acc = bl1[f];
  for (int s = 0; s < 384; ++s) acc += gl[s] * Wl1[s * 128 + f];
  t1s[f] = fmaxf(acc, 0.f);
  __syncthreads();
  if (f < 64) {
    acc = bl2[f];
    for (int s = 0; s < 128; ++s) acc += t1s[s] * Wl2[s * 64 + f];
    t2s[f] = fmaxf(acc, 0.f);
  }
  __syncthreads();
  if (f < 10) {
    acc = bl3[f];
    for (int s = 0; s < 64; ++s) acc += t2s[s] * Wl3[s * 10 + f];
    lg[f] = acc;
  }
  __syncthreads();
  if (f == 0) {
    float m = lg[0];
    for (int c = 1; c < 10; ++c) m = fmaxf(m, lg[c]);
    float s = 0.f;
    for (int c = 0; c < 10; ++c) s += expf(lg[c] - m);
    float l = logf(s);
    for (int c = 0; c < 10; ++c) out[b * 10 + c] = lg[c] - m - l;
  }
}

extern "C" void kernel_launch(void* const* d_in, const int* in_sizes, int n_in,
                              void* d_out, int out_size, void* d_ws, size_t ws_size,
                              hipStream_t stream) {
  const float* x    = (const float*)d_in[0];
  const int*   src  = (const int*)d_in[1];
  const int*   dst  = (const int*)d_in[2];
  const float* skew = (const float*)d_in[3];
  const float* W1   = (const float*)d_in[4];
  const float* b1   = (const float*)d_in[5];
  const float* W2   = (const float*)d_in[6];
  const float* b2   = (const float*)d_in[7];
  const float* W3   = (const float*)d_in[8];
  const float* b3   = (const float*)d_in[9];
  const float* att1 = (const float*)d_in[10];
  const float* att2 = (const float*)d_in[11];
  const float* Wsk  = (const float*)d_in[12];
  const float* bsk  = (const float*)d_in[13];
  const float* Wl1  = (const float*)d_in[14];
  const float* bl1  = (const float*)d_in[15];
  const float* Wl2  = (const float*)d_in[16];
  const float* bl2  = (const float*)d_in[17];
  const float* Wl3  = (const float*)d_in[18];
  const float* bl3  = (const float*)d_in[19];
  float* out = (float*)d_out;

  char* base = (char*)d_ws;
  size_t off = 0;
  auto alloc = [&](size_t bytes) -> void* {
    void* p = base + off;
    off += (bytes + 255) & ~(size_t)255;
    return p;
  };

  unsigned* adj = (unsigned*)alloc((size_t)Bb * N0 * 32 * 4);        // 8 MB
  float* dis0 = (float*)alloc((size_t)Bb * N0 * 4);
  float* dis1 = (float*)alloc((size_t)Bb * N0 * 4);
  int*   degv = (int*)alloc((size_t)Bb * N0 * 4);
  float* bigA = (float*)alloc((size_t)64 * 1024 * 1024);             // 64 MB multi-use
  float* XW  = bigA;                                                  // [B,1024,128]
  float* h1  = bigA + (size_t)Bb * N0 * Fd;                           // [B,1024,128]
  float* A1  = bigA;                                                  // [B,512,512] (after h1 dead)
  float* XW3 = bigA;                                                  // [B,256,128] (after A1 dead)
  float* h3  = bigA + (size_t)Bb * K2 * Fd;                           // [B,256,128]
  float* partial = (float*)alloc((size_t)Bb * N0 * 8 * 4);            // 2 MB; also score2
  int*   perm1 = (int*)alloc((size_t)Bb * K1 * 4);
  float* Xp1 = (float*)alloc((size_t)Bb * K1 * Fd * 4);               // later reused as A2
  float* A2  = Xp1;                                                   // [B,256,256] = same bytes
  float* ar1 = (float*)alloc((size_t)Bb * K1 * 4);
  float* ac1 = (float*)alloc((size_t)Bb * K1 * 4);
  float* disc2 = (float*)alloc((size_t)Bb * K1 * 4);
  float* sa2   = (float*)alloc((size_t)Bb * K1 * 4);
  float* disn2 = (float*)alloc((size_t)Bb * K1 * 4);
  float* diag2 = (float*)alloc((size_t)Bb * K1 * 4);
  float* XW2 = (float*)alloc((size_t)Bb * K1 * Fd * 4);               // 16 MB
  float* h2  = (float*)alloc((size_t)Bb * K1 * Fd * 4);               // 16 MB
  int*   perm2 = (int*)alloc((size_t)Bb * K2 * 4);
  float* Xp2 = (float*)alloc((size_t)Bb * K2 * Fd * 4);
  float* ar2 = (float*)alloc((size_t)Bb * K2 * 4);
  float* ac2 = (float*)alloc((size_t)Bb * K2 * 4);
  float* disc3 = (float*)alloc((size_t)Bb * K2 * 4);
  float* sa3   = (float*)alloc((size_t)Bb * K2 * 4);
  float* disn3 = (float*)alloc((size_t)Bb * K2 * 4);
  float* diag3 = (float*)alloc((size_t)Bb * K2 * 4);
  float* g  = (float*)alloc((size_t)Bb * 384 * 4);
  // nbr [B*N0][128] u16 = 16 MB; overlays XW2 (dead until stage-2 gemm)
  unsigned short* nbr = (unsigned short*)XW2;
  (void)ws_size; (void)in_sizes; (void)n_in; (void)out_size;

  // stage 1: fused graph build, gemm, fused conv+nis (pre-swizzled offsets)
  k_graph<<<Bb * 4, 1024, 0, stream>>>(src, dst, adj, nbr, degv, dis0, dis1);
  k_gemm128<<<Bb * N0 / 64, 256, 0, stream>>>(x, W1, XW);
  k_convnis<<<Bb * 8, 1024, 0, stream>>>(nbr, degv, XW, dis0, dis1, b1, h1, partial);
  k_topk<<<Bb, N0, 0, stream>>>(partial, perm1, N0, K1, 8);
  k_gather<<<Bb * K1, 128, 0, stream>>>(h1, perm1, att1, Xp1, ar1, ac1, N0, K1);
  k_readout<<<Bb, 1024, 0, stream>>>(Xp1, K1, g, 1);
  k_buildA_bit<<<Bb * K1 / 4, 256, 0, stream>>>(adj, perm1, ar1, ac1, A1,
                                                disc2, sa2, disn2, diag2);  // overwrites XW/h1

  // stage 2: dense A1 (MFMA 3xbf16-split mm + fused epilogues)
  k_gemm128<<<Bb * K1 / 64, 256, 0, stream>>>(Xp1, W2, XW2);
  k_mmf<0><<<Bb * (K1 / 64) * 2, 512, 0, stream>>>(A1, XW2, disc2, sa2, b2, h2, K1);
  k_mmf<1><<<Bb * (K1 / 64) * 2, 512, 0, stream>>>(A1, h2, disn2, diag2, nullptr, partial, K1);
  k_topk<<<Bb, K1, 0, stream>>>(partial, perm2, K1, K2, 2);
  k_gather<<<Bb * K2, 128, 0, stream>>>(h2, perm2, att2, Xp2, ar2, ac2, K1, K2);
  k_readout<<<Bb, 1024, 0, stream>>>(Xp2, K2, g, 0);
  k_buildA_dense<<<Bb * K2 / 4, 256, 0, stream>>>(A1, perm2, ar2, ac2, A2,
                                                  disc3, sa3, disn3, diag3);  // overwrites Xp1

  // stage 3: dense A2
  k_gemm128<<<Bb * K2 / 64, 256, 0, stream>>>(Xp2, W3, XW3);           // overwrites A1 region
  k_mmf<0><<<Bb * (K2 / 64) * 2, 512, 0, stream>>>(A2, XW3, disc3, sa3, b3, h3, K2);
  k_readout<<<Bb, 1024, 0, stream>>>(h3, K2, g, 0);

  // fused head
  k_head<<<Bb, 128, 0, stream>>>(g, skew, Wsk, bsk, Wl1, bl1, Wl2, bl2, Wl3, bl3, out);
}